// Round 5
// baseline (17649.312 us; speedup 1.0000x reference)
//
#include <hip/hip_runtime.h>
#include <math.h>

typedef unsigned short u16;

// ---------------- numeric helpers ----------------
__device__ __forceinline__ float bf2f(u16 x){
    unsigned int u = ((unsigned int)x) << 16;
    float f;
    __builtin_memcpy(&f, &u, 4);
    return f;
}
__device__ __forceinline__ u16 f2bf(float f){
    unsigned int u;
    __builtin_memcpy(&u, &f, 4);
    u += 0x7fffu + ((u >> 16) & 1u);
    return (u16)(u >> 16);
}
// mode: 0 = inputs are bf16 on the wire, 1 = inputs are f32 on the wire
__device__ __forceinline__ float ldmix(const void* p, long i, int mode){
    if (mode) return ((const float*)p)[i];
    return bf2f(((const u16*)p)[i]);
}
__device__ __forceinline__ float sigf(float x){ return 1.0f/(1.0f+expf(-x)); }

// ---------------- sizes ----------------
#define BATCH 256
#define TLEN 168
#define HOR 24

// ---------------- workspace layout (bytes) ----------------
#define OFF_FLAG 0ull
#define OFF_SENT 16ull
#define OFF_WF   256ull          // converted weights, f32, 2180353 elems
#define OFF_H0   8721920ull      // 65536 f32
#define OFF_H1   8984064ull      // 65536 f32
#define OFF_C    9246208ull      // 196608 f32
#define OFF_Q    10032640ull     // 196608 f32
#define OFF_GX   10819072ull     // 196608 f32
#define OFF_GH   11605504ull     // 196608 f32
#define OFF_SP   12391936ull     // 65536 f32
#define OFF_E    12654080ull     // 1572864 f32
#define OFF_ENCOUT 18945536ull   // 33030144 u16
#define OFF_PROJ 85005824ull     // 33030144 u16
#define NEED_BYTES 151066112ull

// f32-element offsets inside the converted-weights region
#define W_ENCW 0
#define W_ENCU 73728
#define W_ENCB 663552
#define W_AW1  665856
#define W_AW2  862464
#define W_AV   1059072
#define W_DECW 1059840
#define W_DECU 1650432
#define W_DECB 1847040
#define W_EXTW 1847808
#define W_EXTB 1851904
#define W_O1W  1852160
#define W_O1B  2179840
#define W_O2W  2180096
#define W_O2B  2180352

__device__ const int c_wsz[15]  = {73728,589824,2304,196608,196608,768,590592,196608,768,4096,256,327680,256,256,1};
__device__ const int c_woff[15] = {W_ENCW,W_ENCU,W_ENCB,W_AW1,W_AW2,W_AV,W_DECW,W_DECU,W_DECB,W_EXTW,W_EXTB,W_O1W,W_O1B,W_O2W,W_O2B};

struct P15 { const void* p[15]; };

#define SENT_MAGIC 0x5AFE0000u
__device__ __forceinline__ void put_sent(char* ws, int idx){
    ((unsigned int*)(ws+OFF_SENT))[idx] = SENT_MAGIC | (unsigned int)idx;
}

// =========================================================================
// probe: decide wire dtype. bf16 wire -> max|bf16(enc_W[0:2048])| <= ~0.3;
// f32 wire -> low-mantissa words decode to huge bf16 values (>1000).
// =========================================================================
__global__ __launch_bounds__(256) void k_probe(const u16* w16, char* ws)
{
    __shared__ float red[256];
    int tid = threadIdx.x;
    float mb = 0.0f;
    for (int i = tid; i < 2048; i += 256){
        float a = fabsf(bf2f(w16[i]));
        if (a > mb) mb = a;
    }
    red[tid] = mb;
    __syncthreads();
    if (tid == 0){
        for (int i = 1; i < 256; ++i) if (red[i] > mb) mb = red[i];
        *(int*)(ws+OFF_FLAG) = (mb > 1000.0f) ? 1 : 0;
        put_sent(ws, 0);
    }
}

// =========================================================================
// convert the 15 weight tensors to f32 in ws
// =========================================================================
__global__ __launch_bounds__(256) void k_convert(P15 in, char* ws)
{
    int mode = *(const int*)(ws+OFF_FLAG);
    float* F = (float*)(ws+OFF_WF);
    int y = blockIdx.y;
    int sz = c_wsz[y], off = c_woff[y];
    for (long i = (long)blockIdx.x*256 + threadIdx.x; i < sz; i += 256L*256L)
        F[off + i] = ldmix(in.p[y], i, mode);
    if (blockIdx.x==0 && blockIdx.y==0 && threadIdx.x==0) put_sent(ws, 1);
}

// =========================================================================
// init: zero h0 and c
// =========================================================================
__global__ __launch_bounds__(256) void k_init(char* ws)
{
    long idx = (long)blockIdx.x*256 + threadIdx.x;   // grid 1024
    if (idx < 65536) ((float*)(ws+OFF_H0))[idx] = 0.0f;
    else ((float*)(ws+OFF_C))[idx-65536] = 0.0f;
}

// =========================================================================
// encoder GRU (pure VALU, f32): grid (32 rowtiles of 8, 3 encs), 256 thr.
// thread = gate column; h state in LDS; weights streamed from L2.
// =========================================================================
__global__ __launch_bounds__(256) void k_enc(const void* enc_in, char* ws, u16* enc_out)
{
    const float* F = (const float*)(ws+OFF_WF);
    int mode = *(const int*)(ws+OFF_FLAG);
    const int n = blockIdx.y;
    const int b0 = blockIdx.x*8;
    const int tid = threadIdx.x;

    __shared__ float sh[8][256];
    __shared__ float sx[8][32];
    for (int i = tid; i < 2048; i += 256) ((float*)sh)[i] = 0.0f;

    const float* Wf = F + W_ENCW + n*24576;
    const float* Uf = F + W_ENCU + n*196608;
    const float* bf = F + W_ENCB + n*768;
    float bz = bf[tid], br = bf[256+tid], bn = bf[512+tid];
    __syncthreads();

    for (int t = 0; t < TLEN; ++t){
        {
            int r = tid >> 5, k = tid & 31;
            sx[r][k] = ldmix(enc_in, (((long)(n*BATCH + b0 + r))*TLEN + t)*32 + k, mode);
        }
        __syncthreads();
        float az[8], ar[8], anx[8], anh[8];
        #pragma unroll
        for (int r = 0; r < 8; ++r){ az[r]=bz; ar[r]=br; anx[r]=bn; anh[r]=0.0f; }
        for (int k = 0; k < 32; ++k){
            float w0 = Wf[k*768 + tid];
            float w1 = Wf[k*768 + 256 + tid];
            float w2 = Wf[k*768 + 512 + tid];
            #pragma unroll
            for (int r = 0; r < 8; ++r){
                float xv = sx[r][k];
                az[r]  += xv*w0;
                ar[r]  += xv*w1;
                anx[r] += xv*w2;
            }
        }
        for (int k = 0; k < 256; ++k){
            float u0 = Uf[k*768 + tid];
            float u1 = Uf[k*768 + 256 + tid];
            float u2 = Uf[k*768 + 512 + tid];
            #pragma unroll
            for (int r = 0; r < 8; ++r){
                float hv = sh[r][k];
                az[r]  += hv*u0;
                ar[r]  += hv*u1;
                anh[r] += hv*u2;
            }
        }
        __syncthreads();
        #pragma unroll
        for (int r = 0; r < 8; ++r){
            float z  = sigf(az[r]);
            float rr = sigf(ar[r]);
            float ng = tanhf(anx[r] + rr*anh[r]);
            float hn = (1.0f - z)*sh[r][tid] + z*ng;
            sh[r][tid] = hn;
            enc_out[(((long)(n*BATCH + b0 + r))*TLEN + t)*256 + tid] = f2bf(hn);
        }
        __syncthreads();
    }
    if (blockIdx.x==0 && blockIdx.y==0 && tid==0) put_sent(ws, 2);
}

// =========================================================================
// proj = enc_out @ att_W1[n] : rows are (b*168+t). grid (1344 rowtiles32, 3)
// =========================================================================
__global__ __launch_bounds__(256) void k_proj(char* ws)
{
    const float* F = (const float*)(ws+OFF_WF);
    const u16* enc16 = (const u16*)(ws+OFF_ENCOUT);
    u16* proj = (u16*)(ws+OFF_PROJ);
    const int n = blockIdx.y;
    const long r0 = (long)blockIdx.x*32;
    const int tid = threadIdx.x;

    __shared__ float A[32][256];
    long base = ((long)n*43008 + r0)*256;
    for (int i = tid; i < 8192; i += 256)
        A[i>>8][i&255] = bf2f(enc16[base + i]);
    __syncthreads();

    const float* W1 = F + W_AW1 + n*65536;
    float acc[32];
    #pragma unroll
    for (int r = 0; r < 32; ++r) acc[r] = 0.0f;
    for (int k = 0; k < 256; ++k){
        float w = W1[k*256 + tid];
        #pragma unroll
        for (int r = 0; r < 32; ++r) acc[r] += A[r][k]*w;
    }
    for (int r = 0; r < 32; ++r)
        proj[base + (long)r*256 + tid] = f2bf(acc[r]);
    if (blockIdx.x==0 && blockIdx.y==0 && tid==0) put_sent(ws, 3);
}

// =========================================================================
// decoder gate GEMM: GX = [c,d]@dec_W + b, GH = h@dec_U.
// grid (16 rowtiles16, 3 colgroups), 256 thr, thread = column.
// =========================================================================
__global__ __launch_bounds__(256) void k_dec_gemm(
    char* ws, const float* h_in, const void* dec_in, int step)
{
    const float* F = (const float*)(ws+OFF_WF);
    const float* C = (const float*)(ws+OFF_C);
    float* GX = (float*)(ws+OFF_GX);
    float* GH = (float*)(ws+OFF_GH);
    int mode = *(const int*)(ws+OFF_FLAG);
    const int b0 = blockIdx.x*16;
    const int col = blockIdx.y*256 + threadIdx.x;
    const int tid = threadIdx.x;

    __shared__ float A[16][1025];
    for (int i = tid; i < 16400; i += 256){
        int r = i / 1025, k = i % 1025;
        float v;
        if (k < 768)       v = C[(long)(b0+r)*768 + k];
        else if (k < 1024) v = h_in[(long)(b0+r)*256 + (k-768)];
        else               v = ldmix(dec_in, (long)(b0+r)*HOR + step, mode);
        A[r][k] = v;
    }
    __syncthreads();

    const float* DW = F + W_DECW;
    const float* DU = F + W_DECU;
    float accX[16], accH[16];
    float bcol = F[W_DECB + col];
    #pragma unroll
    for (int r = 0; r < 16; ++r){ accX[r] = bcol; accH[r] = 0.0f; }
    for (int k = 0; k < 768; ++k){
        float w = DW[k*768 + col];
        #pragma unroll
        for (int r = 0; r < 16; ++r) accX[r] += A[r][k]*w;
    }
    {   // the d_t row of dec_W (row 768)
        float w = DW[768*768 + col];
        #pragma unroll
        for (int r = 0; r < 16; ++r) accX[r] += A[r][1024]*w;
    }
    for (int k = 0; k < 256; ++k){
        float u = DU[k*768 + col];
        #pragma unroll
        for (int r = 0; r < 16; ++r) accH[r] += A[r][768+k]*u;
    }
    for (int r = 0; r < 16; ++r){
        GX[(long)(b0+r)*768 + col] = accX[r];
        GH[(long)(b0+r)*768 + col] = accH[r];
    }
}

// =========================================================================
// decoder combine: h' = (1-z)h + z n. grid 256, 256 thr.
// =========================================================================
__global__ __launch_bounds__(256) void k_dec_combine(
    char* ws, const float* h_in, float* h_out)
{
    const float* GX = (const float*)(ws+OFF_GX);
    const float* GH = (const float*)(ws+OFF_GH);
    int b = blockIdx.x, u = threadIdx.x;
    float z  = sigf(GX[(long)b*768 + u]       + GH[(long)b*768 + u]);
    float r  = sigf(GX[(long)b*768 + 256 + u] + GH[(long)b*768 + 256 + u]);
    float ng = tanhf(GX[(long)b*768 + 512 + u] + r*GH[(long)b*768 + 512 + u]);
    h_out[(long)b*256 + u] = (1.0f - z)*h_in[(long)b*256 + u] + z*ng;
}

// =========================================================================
// q[n] = h @ att_W2[n] : grid (8 rowtiles32, 3), 256 thr
// =========================================================================
__global__ __launch_bounds__(256) void k_q(char* ws, const float* h)
{
    const float* F = (const float*)(ws+OFF_WF);
    float* Q = (float*)(ws+OFF_Q);
    const int n = blockIdx.y;
    const int b0 = blockIdx.x*32;
    const int tid = threadIdx.x;

    __shared__ float A[32][256];
    for (int i = tid; i < 8192; i += 256)
        A[i>>8][i&255] = h[(long)b0*256 + i];
    __syncthreads();

    const float* W2 = F + W_AW2 + n*65536;
    float acc[32];
    #pragma unroll
    for (int r = 0; r < 32; ++r) acc[r] = 0.0f;
    for (int k = 0; k < 256; ++k){
        float w = W2[k*256 + tid];
        #pragma unroll
        for (int r = 0; r < 32; ++r) acc[r] += A[r][k]*w;
    }
    for (int r = 0; r < 32; ++r)
        Q[(long)(n*BATCH + b0 + r)*256 + tid] = acc[r];
}

// =========================================================================
// attention: grid (256 b, 3 n), 256 thr
// =========================================================================
__global__ __launch_bounds__(256) void k_attn(char* ws)
{
    const float* F = (const float*)(ws+OFF_WF);
    const float* Q = (const float*)(ws+OFF_Q);
    const u16* proj = (const u16*)(ws+OFF_PROJ);
    const u16* enc16 = (const u16*)(ws+OFF_ENCOUT);
    float* C = (float*)(ws+OFF_C);
    const int b = blockIdx.x, n = blockIdx.y;
    const int tid = threadIdx.x;
    const int w = tid>>6, l = tid&63;

    __shared__ float sc[TLEN];

    float qv[4], vv[4];
    #pragma unroll
    for (int c4 = 0; c4 < 4; ++c4){
        qv[c4] = Q[(long)(n*BATCH + b)*256 + c4*64 + l];
        vv[c4] = F[W_AV + n*256 + c4*64 + l];
    }
    long base = ((long)n*43008 + (long)b*TLEN)*256;
    const u16* pb = proj + base;
    for (int i = 0; i < 42; ++i){
        int t = w*42 + i;
        float s = 0.0f;
        #pragma unroll
        for (int c4 = 0; c4 < 4; ++c4){
            float pv = bf2f(pb[(long)t*256 + c4*64 + l]);
            s += vv[c4]*tanhf(pv + qv[c4]);
        }
        for (int off = 32; off > 0; off >>= 1) s += __shfl_xor(s, off, 64);
        if (l == 0) sc[t] = s;
    }
    __syncthreads();
    float mx = -1e30f;
    for (int t = 0; t < TLEN; ++t) if (sc[t] > mx) mx = sc[t];
    __syncthreads();
    if (tid < TLEN) sc[tid] = expf(sc[tid]-mx);
    __syncthreads();
    float sum = 0.0f;
    for (int t = 0; t < TLEN; ++t) sum += sc[t];
    float inv = 1.0f/sum;
    const u16* eb = enc16 + base;
    float acc = 0.0f;
    for (int t = 0; t < TLEN; ++t) acc += sc[t]*bf2f(eb[(long)t*256 + tid]);
    C[(long)b*768 + n*256 + tid] = acc*inv;
    if (b==0 && n==0 && tid==0) put_sent(ws, 4);
}

// =========================================================================
// head1: sp = [h,c] @ out1_W[0:1024] : grid 16 rowtiles16, 256 thr
// =========================================================================
__global__ __launch_bounds__(256) void k_head1(char* ws, const float* h_last)
{
    const float* F = (const float*)(ws+OFF_WF);
    const float* C = (const float*)(ws+OFF_C);
    float* SP = (float*)(ws+OFF_SP);
    const int b0 = blockIdx.x*16;
    const int tid = threadIdx.x;

    __shared__ float A[16][1024];
    for (int i = tid; i < 16384; i += 256){
        int r = i >> 10, k = i & 1023;
        A[r][k] = (k < 256) ? h_last[(long)(b0+r)*256 + k]
                            : C[(long)(b0+r)*768 + (k-256)];
    }
    __syncthreads();

    const float* W = F + W_O1W;
    float acc[16];
    float bc = F[W_O1B + tid];
    #pragma unroll
    for (int r = 0; r < 16; ++r) acc[r] = bc;
    for (int k = 0; k < 1024; ++k){
        float w = W[k*256 + tid];
        #pragma unroll
        for (int r = 0; r < 16; ++r) acc[r] += A[r][k]*w;
    }
    for (int r = 0; r < 16; ++r)
        SP[(long)(b0+r)*256 + tid] = acc[r];
}

// =========================================================================
// ext: E = relu(ext_feat @ ext_W + ext_b) : grid 96 (64-row tiles), 256 thr
// =========================================================================
__global__ __launch_bounds__(256) void k_ext(const void* ext_feat, char* ws)
{
    const float* F = (const float*)(ws+OFF_WF);
    float* E = (float*)(ws+OFF_E);
    int mode = *(const int*)(ws+OFF_FLAG);
    const int r0 = blockIdx.x*64;
    const int tid = threadIdx.x;
    __shared__ float ef[64][16];
    for (int i = tid; i < 1024; i += 256)
        ef[i>>4][i&15] = ldmix(ext_feat, (long)(r0 + (i>>4))*16 + (i&15), mode);
    float wreg[16];
    #pragma unroll
    for (int k = 0; k < 16; ++k) wreg[k] = F[W_EXTW + k*256 + tid];
    float bb = F[W_EXTB + tid];
    __syncthreads();
    for (int r = 0; r < 64; ++r){
        float a = bb;
        #pragma unroll
        for (int k = 0; k < 16; ++k) a += ef[r][k]*wreg[k];
        E[(long)(r0+r)*256 + tid] = (a > 0.0f) ? a : 0.0f;
    }
}

// =========================================================================
// head2: x1 = relu(sp[b] + E@out1_W[1024:] + b1); out = x1@out2_W + b2
// grid 384 (16-row tiles of the 6144 (b,h) rows), 256 thr
// =========================================================================
__global__ __launch_bounds__(256) void k_head2(char* ws, void* out)
{
    const float* F = (const float*)(ws+OFF_WF);
    const float* E = (const float*)(ws+OFF_E);
    const float* SP = (const float*)(ws+OFF_SP);
    int mode = *(const int*)(ws+OFF_FLAG);
    const int r0 = blockIdx.x*16;
    const int tid = threadIdx.x;
    const int w = tid>>6, l = tid&63;

    __shared__ float A[16][256];
    __shared__ float x1[16][257];
    for (int i = tid; i < 4096; i += 256)
        A[i>>8][i&255] = E[(long)r0*256 + i];
    __syncthreads();

    const float* W = F + W_O1W + 1024*256;
    float acc[16];
    float bc = F[W_O1B + tid];
    #pragma unroll
    for (int r = 0; r < 16; ++r) acc[r] = 0.0f;
    for (int k = 0; k < 256; ++k){
        float wv = W[k*256 + tid];
        #pragma unroll
        for (int r = 0; r < 16; ++r) acc[r] += A[r][k]*wv;
    }
    for (int r = 0; r < 16; ++r){
        int g = r0 + r;
        int b = g / HOR;
        float v = acc[r] + SP[(long)b*256 + tid] + bc;
        x1[r][tid] = (v > 0.0f) ? v : 0.0f;
    }
    __syncthreads();

    float w2v[4];
    #pragma unroll
    for (int c4 = 0; c4 < 4; ++c4) w2v[c4] = F[W_O2W + c4*64 + l];
    float b2 = F[W_O2B];
    #pragma unroll
    for (int rr = 0; rr < 4; ++rr){
        int m = w*4 + rr;
        float s = 0.0f;
        #pragma unroll
        for (int c4 = 0; c4 < 4; ++c4) s += x1[m][c4*64 + l]*w2v[c4];
        for (int off = 32; off > 0; off >>= 1) s += __shfl_xor(s, off, 64);
        if (l == 0){
            float val = s + b2;
            long g = r0 + m;
            if (mode == 0) ((u16*)out)[g] = f2bf(val);
            else           ((float*)out)[g] = val;
        }
    }
    if (blockIdx.x==0 && tid==0) put_sent(ws, 5);
}

// =========================================================================
// checker: writes 400+10*i to out[0] if sentinel i missing
// =========================================================================
__global__ __launch_bounds__(64) void MTANet_7593502179851_kernel(char* ws, void* out)
{
    if (threadIdx.x == 0){
        const unsigned int* sent = (const unsigned int*)(ws+OFF_SENT);
        int mode = *(const int*)(ws+OFF_FLAG);
        for (int i = 0; i < 6; ++i){
            if (sent[i] != (SENT_MAGIC | (unsigned int)i)){
                float code = 400.0f + 10.0f*(float)i;
                if (mode == 0) ((u16*)out)[0] = f2bf(code);
                else           ((float*)out)[0] = code;
                break;
            }
        }
    }
}

// diag: write code into out under BOTH dtype interpretations (out[0] bf16,
// out elems [2..3] as one f32) — any non-baseline absmax is signal.
__global__ __launch_bounds__(64) void k_diag(void* out, float code)
{
    if (threadIdx.x == 0){
        ((u16*)out)[0] = f2bf(code);
        ((float*)out)[1] = code;
    }
}

// =========================================================================
extern "C" void kernel_launch(void* const* d_in, const int* in_sizes, int n_in,
                              void* d_out, int out_size, void* d_ws, size_t ws_size,
                              hipStream_t stream)
{
    char* ws = (char*)d_ws;

    // ---- input table validation (code 900+i) ----
    static const int exp_sizes[18] = {
        4128768, 6144, 98304, 73728, 589824, 2304, 196608, 196608, 768,
        590592, 196608, 768, 4096, 256, 327680, 256, 256, 1 };
    int bad_i = -1;
    if (n_in != 18) bad_i = 99;
    else for (int i = 0; i < 18; ++i)
        if (in_sizes[i] != exp_sizes[i]){ bad_i = i; break; }
    if (bad_i >= 0){
        k_diag<<<dim3(1), dim3(64), 0, stream>>>(d_out, 900.0f + (float)bad_i);
        return;
    }
    // ---- workspace size validation (code 600) ----
    if (ws_size < (size_t)NEED_BYTES){
        k_diag<<<dim3(1), dim3(64), 0, stream>>>(d_out, 600.0f);
        return;
    }

    P15 wp;
    for (int i = 0; i < 15; ++i) wp.p[i] = d_in[3+i];

    hipError_t le[12];
    for (int i = 0; i < 12; ++i) le[i] = hipSuccess;
    (void)hipGetLastError();
    #define CHK(slot) { hipError_t e_ = hipGetLastError(); if (e_ != hipSuccess && le[slot] == hipSuccess) le[slot] = e_; }

    k_probe<<<dim3(1), dim3(256), 0, stream>>>((const u16*)d_in[3], ws);       CHK(0)
    k_convert<<<dim3(256,15), dim3(256), 0, stream>>>(wp, ws);                 CHK(1)
    k_init<<<dim3(1024), dim3(256), 0, stream>>>(ws);                          CHK(2)
    k_enc<<<dim3(32,3), dim3(256), 0, stream>>>(d_in[0], ws, (u16*)(ws+OFF_ENCOUT)); CHK(3)
    k_proj<<<dim3(1344,3), dim3(256), 0, stream>>>(ws);                        CHK(4)

    float* hbuf0 = (float*)(ws+OFF_H0);
    float* hbuf1 = (float*)(ws+OFF_H1);
    float* h_last = hbuf0;
    for (int s = 0; s < HOR; ++s){
        float* h_in  = (s & 1) ? hbuf1 : hbuf0;
        float* h_out = (s & 1) ? hbuf0 : hbuf1;
        k_dec_gemm<<<dim3(16,3), dim3(256), 0, stream>>>(ws, h_in, d_in[1], s); CHK(5)
        k_dec_combine<<<dim3(256), dim3(256), 0, stream>>>(ws, h_in, h_out);    CHK(6)
        k_q<<<dim3(8,3), dim3(256), 0, stream>>>(ws, h_out);                    CHK(7)
        k_attn<<<dim3(256,3), dim3(256), 0, stream>>>(ws);                      CHK(8)
        h_last = h_out;
    }
    k_head1<<<dim3(16), dim3(256), 0, stream>>>(ws, h_last);                   CHK(9)
    k_ext<<<dim3(96), dim3(256), 0, stream>>>(d_in[2], ws);                    CHK(10)
    k_head2<<<dim3(384), dim3(256), 0, stream>>>(ws, d_out);                   CHK(11)
    MTANet_7593502179851_kernel<<<dim3(1), dim3(64), 0, stream>>>(ws, d_out);
    #undef CHK

    // ---- launch-error report (code 800+slot) ----
    for (int i = 0; i < 12; ++i){
        if (le[i] != hipSuccess){
            k_diag<<<dim3(1), dim3(64), 0, stream>>>(d_out, 800.0f + (float)i);
            break;
        }
    }
}

// Round 6
// 7240.935 us; speedup vs baseline: 2.4374x; 2.4374x over previous
//
#include <hip/hip_runtime.h>
#include <math.h>

typedef unsigned short u16;
typedef float f4v __attribute__((ext_vector_type(4)));
typedef __bf16 bfv8 __attribute__((ext_vector_type(8)));

// gfx950 MFMA: D = A(16x32 bf16) * B(32x16 bf16) + C(f32x4)
#define MFMA16(a,b,c) __builtin_amdgcn_mfma_f32_16x16x32_bf16((a),(b),(c),0,0,0)

// ---------------- numeric helpers ----------------
__device__ __forceinline__ float bf2f(u16 x){
    unsigned int u = ((unsigned int)x) << 16;
    float f; __builtin_memcpy(&f, &u, 4); return f;
}
__device__ __forceinline__ u16 f2bf(float f){
    unsigned int u; __builtin_memcpy(&u, &f, 4);
    u += 0x7fffu + ((u >> 16) & 1u);
    return (u16)(u >> 16);
}
// mode: 0 = bf16 wire, 1 = f32 wire
__device__ __forceinline__ float ldmix(const void* p, long i, int mode){
    if (mode) return ((const float*)p)[i];
    return bf2f(((const u16*)p)[i]);
}
__device__ __forceinline__ float sigf(float x){ return 1.0f/(1.0f+expf(-x)); }

// ---------------- sizes ----------------
#define BATCH 256
#define TLEN 168
#define HOR 24

// ---------------- workspace layout (bytes) ----------------
#define OFF_FLAG 0ull
#define OFF_SENT 16ull
#define OFF_WF   256ull          // f32 weights, 2180353 elems
#define OFF_UP   8721920ull      // packed enc_U  3*196608 u16
#define OFF_WP   9901568ull      // packed enc_W  3*24576 u16
#define OFF_DWP  10049024ull     // packed dec_W rows 0..767, 589824 u16
#define OFF_DUP  11228672ull     // packed dec_U 196608 u16
#define OFF_H0   11621888ull     // 65536 f32
#define OFF_H1   11884032ull     // 65536 f32
#define OFF_C    12146176ull     // 196608 f32
#define OFF_Q    12932608ull     // 196608 f32
#define OFF_SP   13719040ull     // 65536 f32
#define OFF_E    13981184ull     // 1572864 u16 (bf16)
#define OFF_ENCOUT 17126912ull   // 33030144 u16
#define OFF_PROJ 83187200ull     // 33030144 u16
#define NEED_BYTES 149247488ull  // < proven-available 151066112

// f32-element offsets inside the converted-weights region
#define W_ENCW 0
#define W_ENCU 73728
#define W_ENCB 663552
#define W_AW1  665856
#define W_AW2  862464
#define W_AV   1059072
#define W_DECW 1059840
#define W_DECU 1650432
#define W_DECB 1847040
#define W_EXTW 1847808
#define W_EXTB 1851904
#define W_O1W  1852160
#define W_O1B  2179840
#define W_O2W  2180096
#define W_O2B  2180352

__device__ const int c_wsz[15]  = {73728,589824,2304,196608,196608,768,590592,196608,768,4096,256,327680,256,256,1};
__device__ const int c_woff[15] = {W_ENCW,W_ENCU,W_ENCB,W_AW1,W_AW2,W_AV,W_DECW,W_DECU,W_DECB,W_EXTW,W_EXTB,W_O1W,W_O1B,W_O2W,W_O2B};

struct P15 { const void* p[15]; };

#define SENT_MAGIC 0x5AFE0000u
__device__ __forceinline__ void put_sent(char* ws, int idx){
    ((unsigned int*)(ws+OFF_SENT))[idx] = SENT_MAGIC | (unsigned int)idx;
}

// =========================================================================
// probe: decide wire dtype (bf16 reinterpretation of f32 words is huge)
// =========================================================================
__global__ __launch_bounds__(256) void k_probe(const u16* w16, char* ws)
{
    __shared__ float red[256];
    int tid = threadIdx.x;
    float mb = 0.0f;
    for (int i = tid; i < 2048; i += 256){
        float a = fabsf(bf2f(w16[i]));
        if (a > mb) mb = a;
    }
    red[tid] = mb;
    __syncthreads();
    if (tid == 0){
        for (int i = 1; i < 256; ++i) if (red[i] > mb) mb = red[i];
        *(int*)(ws+OFF_FLAG) = (mb > 1000.0f) ? 1 : 0;
        put_sent(ws, 0);
    }
}

// =========================================================================
// convert the 15 weight tensors to f32 in ws
// =========================================================================
__global__ __launch_bounds__(256) void k_convert(P15 in, char* ws)
{
    int mode = *(const int*)(ws+OFF_FLAG);
    float* F = (float*)(ws+OFF_WF);
    int y = blockIdx.y;
    int sz = c_wsz[y], off = c_woff[y];
    for (long i = (long)blockIdx.x*256 + threadIdx.x; i < sz; i += 256L*256L)
        F[off + i] = ldmix(in.p[y], i, mode);
    if (blockIdx.x==0 && blockIdx.y==0 && threadIdx.x==0) put_sent(ws, 1);
}

// =========================================================================
// pack: F(f32 row-major [K][N]) -> bf16 MFMA B-frags (K=32 tiles):
//   dst[((ct*KT+kt)*64 + l)*8 + j] = src[(kt*32 + (l>>4)*8 + j)*N + ct*16 + (l&15)]
// =========================================================================
__global__ __launch_bounds__(64) void k_pack(char* ws)
{
    const float* F = (const float*)(ws+OFF_WF);
    int m = blockIdx.y;
    const float* src; u16* dst; int K, N;
    switch (m) {
      case 0: case 1: case 2:
        src = F + W_ENCU + m*196608; dst = (u16*)(ws+OFF_UP) + m*196608; K=256; N=768; break;
      case 3: case 4: case 5:
        src = F + W_ENCW + (m-3)*24576; dst = (u16*)(ws+OFF_WP) + (m-3)*24576; K=32; N=768; break;
      case 6:
        src = F + W_DECW; dst = (u16*)(ws+OFF_DWP); K=768; N=768; break;
      default:
        src = F + W_DECU; dst = (u16*)(ws+OFF_DUP); K=256; N=768; break;
    }
    int KT = K>>5, NT = N>>4;
    int tau = blockIdx.x;
    if (tau < KT*NT){
        int ct = tau / KT, kt = tau % KT;
        int l = threadIdx.x, q = l>>4, c = l&15;
        #pragma unroll
        for (int j = 0; j < 8; ++j)
            dst[((size_t)(ct*KT+kt)*64 + l)*8 + j] = f2bf(src[(size_t)(kt*32 + q*8 + j)*N + ct*16 + c]);
    }
    if (blockIdx.x==0 && blockIdx.y==0 && threadIdx.x==0) put_sent(ws, 6);
}

// =========================================================================
__global__ __launch_bounds__(256) void k_init(char* ws)
{
    long idx = (long)blockIdx.x*256 + threadIdx.x;
    if (idx < 65536) ((float*)(ws+OFF_H0))[idx] = 0.0f;
    else ((float*)(ws+OFF_C))[idx-65536] = 0.0f;
}

// =========================================================================
// encoder GRU (MFMA): grid (16 rowtiles16, 3 encs), 256 thr (4 waves).
// h f32 in regs; hi/lo bf16 A-frags double-buffered in LDS; packed weights.
// =========================================================================
__global__ __launch_bounds__(256) void k_enc(const void* enc_in, char* ws, u16* enc_out)
{
    const float* F = (const float*)(ws+OFF_WF);
    int mode = *(const int*)(ws+OFF_FLAG);
    const int n  = blockIdx.y;
    const int b0 = blockIdx.x*16;
    const int tid = threadIdx.x;
    const int w = tid>>6, l = tid&63, quad = l>>4, c15 = l&15;

    __shared__ __align__(16) u16 hAhi[2][8][64][8];
    __shared__ __align__(16) u16 hAlo[2][8][64][8];
    __shared__ __align__(16) u16 sx[64][8];

    {
        int* z0 = (int*)&hAhi[0][0][0][0];
        int* z1 = (int*)&hAlo[0][0][0][0];
        for (int i = tid; i < 4096; i += 256){ z0[i]=0; z1[i]=0; }
    }
    float h[16];
    #pragma unroll
    for (int i=0;i<16;++i) h[i]=0.0f;

    float bzr[4], brr[4], bnr[4];
    #pragma unroll
    for (int si=0;si<4;++si){
        int u = (w*4+si)*16 + c15;
        bzr[si] = F[W_ENCB + n*768 + u];
        brr[si] = F[W_ENCB + n*768 + 256 + u];
        bnr[si] = F[W_ENCB + n*768 + 512 + u];
    }
    __syncthreads();

    const u16* upn = (const u16*)(ws+OFF_UP) + n*196608;   // KT=8
    const u16* wpn = (const u16*)(ws+OFF_WP) + n*24576;    // KT=1

    for (int t = 0; t < TLEN; ++t){
        int p = t & 1;
        // stage x(t) as A-frag (one K32 tile)
        for (int i = tid; i < 512; i += 256){
            int m = i>>5, k = i&31;
            sx[(k>>3)*16 + m][k&7] =
                f2bf(ldmix(enc_in, (((long)(n*BATCH + b0 + m))*TLEN + t)*32 + k, mode));
        }
        __syncthreads();

        bfv8 ah[8], al[8];
        #pragma unroll
        for (int kt=0; kt<8; ++kt){
            ah[kt] = *(const bfv8*)&hAhi[p][kt][l][0];
            al[kt] = *(const bfv8*)&hAlo[p][kt][l][0];
        }
        bfv8 ax = *(const bfv8*)&sx[l][0];

        #pragma unroll
        for (int si=0; si<4; ++si){
            int ctz = w*4 + si;
            int ctr = 16 + ctz;
            int ctn = 32 + ctz;
            f4v az = {0.f,0.f,0.f,0.f}, ar = {0.f,0.f,0.f,0.f};
            f4v anx = {0.f,0.f,0.f,0.f}, anh = {0.f,0.f,0.f,0.f};
            az  = MFMA16(ax, *(const bfv8*)(wpn + ((size_t)ctz*64 + l)*8), az);
            ar  = MFMA16(ax, *(const bfv8*)(wpn + ((size_t)ctr*64 + l)*8), ar);
            anx = MFMA16(ax, *(const bfv8*)(wpn + ((size_t)ctn*64 + l)*8), anx);
            #pragma unroll
            for (int kt=0; kt<8; ++kt){
                bfv8 bb = *(const bfv8*)(upn + ((size_t)(ctz*8+kt)*64 + l)*8);
                az = MFMA16(ah[kt], bb, az);
                az = MFMA16(al[kt], bb, az);
            }
            #pragma unroll
            for (int kt=0; kt<8; ++kt){
                bfv8 bb = *(const bfv8*)(upn + ((size_t)(ctr*8+kt)*64 + l)*8);
                ar = MFMA16(ah[kt], bb, ar);
                ar = MFMA16(al[kt], bb, ar);
            }
            #pragma unroll
            for (int kt=0; kt<8; ++kt){
                bfv8 bb = *(const bfv8*)(upn + ((size_t)(ctn*8+kt)*64 + l)*8);
                anh = MFMA16(ah[kt], bb, anh);
                anh = MFMA16(al[kt], bb, anh);
            }
            int u = ctz*16 + c15;
            #pragma unroll
            for (int j=0;j<4;++j){
                int m = quad*4 + j;
                float z = sigf(az[j] + bzr[si]);
                float r = sigf(ar[j] + brr[si]);
                float ng = tanhf(anx[j] + bnr[si] + r*anh[j]);
                float hn = (1.0f - z)*h[si*4+j] + z*ng;
                h[si*4+j] = hn;
                enc_out[(((long)(n*BATCH + b0 + m))*TLEN + t)*256 + u] = f2bf(hn);
                u16 hi = f2bf(hn);
                u16 lo = f2bf(hn - bf2f(hi));
                int kt = u>>5, q2 = (u>>3)&3, j2 = u&7;
                hAhi[1-p][kt][q2*16+m][j2] = hi;
                hAlo[1-p][kt][q2*16+m][j2] = lo;
            }
        }
        __syncthreads();
    }
    if (blockIdx.x==0 && blockIdx.y==0 && tid==0) put_sent(ws, 2);
}

// =========================================================================
// proj = enc_out @ att_W1[n] (VALU): grid (1344 rowtiles32, 3), 256 thr
// =========================================================================
__global__ __launch_bounds__(256) void k_proj(char* ws)
{
    const float* F = (const float*)(ws+OFF_WF);
    const u16* enc16 = (const u16*)(ws+OFF_ENCOUT);
    u16* proj = (u16*)(ws+OFF_PROJ);
    const int n = blockIdx.y;
    const long r0 = (long)blockIdx.x*32;
    const int tid = threadIdx.x;

    __shared__ float A[32][256];
    long base = ((long)n*43008 + r0)*256;
    for (int i = tid; i < 8192; i += 256)
        A[i>>8][i&255] = bf2f(enc16[base + i]);
    __syncthreads();

    const float* W1 = F + W_AW1 + n*65536;
    float acc[32];
    #pragma unroll
    for (int r = 0; r < 32; ++r) acc[r] = 0.0f;
    for (int k = 0; k < 256; ++k){
        float w = W1[k*256 + tid];
        #pragma unroll
        for (int r = 0; r < 32; ++r) acc[r] += A[r][k]*w;
    }
    for (int r = 0; r < 32; ++r)
        proj[base + (long)r*256 + tid] = f2bf(acc[r]);
    if (blockIdx.x==0 && blockIdx.y==0 && tid==0) put_sent(ws, 3);
}

// =========================================================================
// decoder GRU step (MFMA, fused gates): grid (16 rowtiles16, 16 u-slices),
// 192 thr (wave = gate). A = [c(768) | h(256)] hi/lo staged in LDS.
// =========================================================================
__global__ __launch_bounds__(192) void k_dec_gru(
    char* ws, const float* h_in, float* h_out, const void* dec_in, int step)
{
    const float* F = (const float*)(ws+OFF_WF);
    const float* C = (const float*)(ws+OFF_C);
    int mode = *(const int*)(ws+OFF_FLAG);
    const u16* dwp = (const u16*)(ws+OFF_DWP);   // KT=24
    const u16* dup = (const u16*)(ws+OFF_DUP);   // KT=8
    const int b0 = blockIdx.x*16;
    const int us = blockIdx.y;
    const int u0 = us*16;
    const int tid = threadIdx.x;
    const int gate = tid>>6, l = tid&63, quad = l>>4, c15 = l&15;
    const int ct = gate*16 + us;

    __shared__ __align__(16) u16 aH[16][64][8];
    __shared__ __align__(16) u16 aL[16][64][8];
    __shared__ float gz[16][16], gr[16][16], gx[16][16], gh[16][16];

    f4v accA = {0.f,0.f,0.f,0.f};
    f4v accB = {0.f,0.f,0.f,0.f};

    for (int half = 0; half < 2; ++half){
        __syncthreads();
        for (int e = tid; e < 8192; e += 192){
            int m = e>>9, kk = e&511;
            int kg = half*512 + kk;
            float v = (kg < 768) ? C[(long)(b0+m)*768 + kg]
                                 : h_in[(long)(b0+m)*256 + kg - 768];
            u16 hi = f2bf(v);
            u16 lo = f2bf(v - bf2f(hi));
            int ktl = kk>>5, q2 = (kk>>3)&3, j2 = kk&7;
            aH[ktl][q2*16+m][j2] = hi;
            aL[ktl][q2*16+m][j2] = lo;
        }
        __syncthreads();
        #pragma unroll
        for (int ktl = 0; ktl < 16; ++ktl){
            int kg = half*16 + ktl;
            const u16* bp = (kg < 24) ? dwp + ((size_t)(ct*24 + kg)*64 + l)*8
                                      : dup + ((size_t)(ct*8  + (kg-24))*64 + l)*8;
            bfv8 bb = *(const bfv8*)bp;
            bfv8 ah = *(const bfv8*)&aH[ktl][l][0];
            bfv8 al = *(const bfv8*)&aL[ktl][l][0];
            if (gate == 2 && kg >= 24){
                accB = MFMA16(ah, bb, accB);
                accB = MFMA16(al, bb, accB);
            } else {
                accA = MFMA16(ah, bb, accA);
                accA = MFMA16(al, bb, accA);
            }
        }
    }
    #pragma unroll
    for (int j=0;j<4;++j){
        int m = quad*4 + j;
        if (gate == 0) gz[m][c15] = accA[j];
        else if (gate == 1) gr[m][c15] = accA[j];
        else { gx[m][c15] = accA[j]; gh[m][c15] = accB[j]; }
    }
    __syncthreads();
    for (int e = tid; e < 256; e += 192){
        int m = e>>4, j = e&15;
        int u = u0 + j;
        int b = b0 + m;
        float db = ldmix(dec_in, (long)b*HOR + step, mode);
        float sz = gz[m][j] + db*F[W_DECW + 768*768 + u]       + F[W_DECB + u];
        float sr = gr[m][j] + db*F[W_DECW + 768*768 + 256 + u] + F[W_DECB + 256 + u];
        float sn = gx[m][j] + db*F[W_DECW + 768*768 + 512 + u] + F[W_DECB + 512 + u];
        float z = sigf(sz);
        float r = sigf(sr);
        float ng = tanhf(sn + r*gh[m][j]);
        h_out[(long)b*256 + u] = (1.0f - z)*h_in[(long)b*256 + u] + z*ng;
    }
}

// =========================================================================
// q[n] = h @ att_W2[n] (VALU): grid (32 rowtiles8, 3), 256 thr
// =========================================================================
__global__ __launch_bounds__(256) void k_q(char* ws, const float* h)
{
    const float* F = (const float*)(ws+OFF_WF);
    float* Q = (float*)(ws+OFF_Q);
    const int n = blockIdx.y;
    const int b0 = blockIdx.x*8;
    const int tid = threadIdx.x;

    __shared__ float A[8][256];
    for (int i = tid; i < 2048; i += 256)
        A[i>>8][i&255] = h[(long)b0*256 + i];
    __syncthreads();

    const float* W2 = F + W_AW2 + n*65536;
    float acc[8];
    #pragma unroll
    for (int r = 0; r < 8; ++r) acc[r] = 0.0f;
    for (int k = 0; k < 256; ++k){
        float w = W2[k*256 + tid];
        #pragma unroll
        for (int r = 0; r < 8; ++r) acc[r] += A[r][k]*w;
    }
    for (int r = 0; r < 8; ++r)
        Q[(long)(n*BATCH + b0 + r)*256 + tid] = acc[r];
}

// =========================================================================
// attention: grid (256 b, 3 n), 256 thr
// =========================================================================
__global__ __launch_bounds__(256) void k_attn(char* ws)
{
    const float* F = (const float*)(ws+OFF_WF);
    const float* Q = (const float*)(ws+OFF_Q);
    const u16* proj = (const u16*)(ws+OFF_PROJ);
    const u16* enc16 = (const u16*)(ws+OFF_ENCOUT);
    float* C = (float*)(ws+OFF_C);
    const int b = blockIdx.x, n = blockIdx.y;
    const int tid = threadIdx.x;
    const int w = tid>>6, l = tid&63;

    __shared__ float sc[TLEN];

    float qv[4], vv[4];
    #pragma unroll
    for (int c4 = 0; c4 < 4; ++c4){
        qv[c4] = Q[(long)(n*BATCH + b)*256 + c4*64 + l];
        vv[c4] = F[W_AV + n*256 + c4*64 + l];
    }
    long base = ((long)n*43008 + (long)b*TLEN)*256;
    const u16* pb = proj + base;
    for (int i = 0; i < 42; ++i){
        int t = w*42 + i;
        float s = 0.0f;
        #pragma unroll
        for (int c4 = 0; c4 < 4; ++c4){
            float pv = bf2f(pb[(long)t*256 + c4*64 + l]);
            s += vv[c4]*tanhf(pv + qv[c4]);
        }
        for (int off = 32; off > 0; off >>= 1) s += __shfl_xor(s, off, 64);
        if (l == 0) sc[t] = s;
    }
    __syncthreads();
    float mx = -1e30f;
    for (int t = 0; t < TLEN; ++t) if (sc[t] > mx) mx = sc[t];
    __syncthreads();
    if (tid < TLEN) sc[tid] = expf(sc[tid]-mx);
    __syncthreads();
    float sum = 0.0f;
    for (int t = 0; t < TLEN; ++t) sum += sc[t];
    float inv = 1.0f/sum;
    const u16* eb = enc16 + base;
    float acc = 0.0f;
    #pragma unroll 4
    for (int t = 0; t < TLEN; ++t) acc += sc[t]*bf2f(eb[(long)t*256 + tid]);
    C[(long)b*768 + n*256 + tid] = acc*inv;
    if (b==0 && n==0 && tid==0) put_sent(ws, 4);
}

// =========================================================================
// head1: sp = [h,c] @ out1_W[0:1024] : grid 32 rowtiles8, 256 thr
// =========================================================================
__global__ __launch_bounds__(256) void k_head1(char* ws, const float* h_last)
{
    const float* F = (const float*)(ws+OFF_WF);
    const float* C = (const float*)(ws+OFF_C);
    float* SP = (float*)(ws+OFF_SP);
    const int b0 = blockIdx.x*8;
    const int tid = threadIdx.x;

    __shared__ float A[8][1024];
    for (int i = tid; i < 8192; i += 256){
        int r = i >> 10, k = i & 1023;
        A[r][k] = (k < 256) ? h_last[(long)(b0+r)*256 + k]
                            : C[(long)(b0+r)*768 + (k-256)];
    }
    __syncthreads();

    const float* W = F + W_O1W;
    float acc[8];
    float bc = F[W_O1B + tid];
    #pragma unroll
    for (int r = 0; r < 8; ++r) acc[r] = bc;
    for (int k = 0; k < 1024; ++k){
        float w = W[k*256 + tid];
        #pragma unroll
        for (int r = 0; r < 8; ++r) acc[r] += A[r][k]*w;
    }
    for (int r = 0; r < 8; ++r)
        SP[(long)(b0+r)*256 + tid] = acc[r];
}

// =========================================================================
// ext: E = relu(ext_feat @ ext_W + ext_b) -> bf16 : grid 96, 256 thr
// =========================================================================
__global__ __launch_bounds__(256) void k_ext(const void* ext_feat, char* ws)
{
    const float* F = (const float*)(ws+OFF_WF);
    u16* E = (u16*)(ws+OFF_E);
    int mode = *(const int*)(ws+OFF_FLAG);
    const int r0 = blockIdx.x*64;
    const int tid = threadIdx.x;
    __shared__ float ef[64][16];
    for (int i = tid; i < 1024; i += 256)
        ef[i>>4][i&15] = ldmix(ext_feat, (long)(r0 + (i>>4))*16 + (i&15), mode);
    float wreg[16];
    #pragma unroll
    for (int k = 0; k < 16; ++k) wreg[k] = F[W_EXTW + k*256 + tid];
    float bb = F[W_EXTB + tid];
    __syncthreads();
    for (int r = 0; r < 64; ++r){
        float a = bb;
        #pragma unroll
        for (int k = 0; k < 16; ++k) a += ef[r][k]*wreg[k];
        E[(long)(r0+r)*256 + tid] = f2bf((a > 0.0f) ? a : 0.0f);
    }
}

// =========================================================================
// head2: x1 = relu(sp[b] + E@out1_W[1024:] + b1); out = x1@out2_W + b2
// =========================================================================
__global__ __launch_bounds__(256) void k_head2(char* ws, void* out)
{
    const float* F = (const float*)(ws+OFF_WF);
    const u16* E = (const u16*)(ws+OFF_E);
    const float* SP = (const float*)(ws+OFF_SP);
    int mode = *(const int*)(ws+OFF_FLAG);
    const int r0 = blockIdx.x*16;
    const int tid = threadIdx.x;
    const int w = tid>>6, l = tid&63;

    __shared__ float A[16][256];
    __shared__ float x1[16][257];
    for (int i = tid; i < 4096; i += 256)
        A[i>>8][i&255] = bf2f(E[(long)r0*256 + i]);
    __syncthreads();

    const float* W = F + W_O1W + 1024*256;
    float acc[16];
    float bc = F[W_O1B + tid];
    #pragma unroll
    for (int r = 0; r < 16; ++r) acc[r] = 0.0f;
    for (int k = 0; k < 256; ++k){
        float wv = W[k*256 + tid];
        #pragma unroll
        for (int r = 0; r < 16; ++r) acc[r] += A[r][k]*wv;
    }
    for (int r = 0; r < 16; ++r){
        int g = r0 + r;
        int b = g / HOR;
        float v = acc[r] + SP[(long)b*256 + tid] + bc;
        x1[r][tid] = (v > 0.0f) ? v : 0.0f;
    }
    __syncthreads();

    float w2v[4];
    #pragma unroll
    for (int c4 = 0; c4 < 4; ++c4) w2v[c4] = F[W_O2W + c4*64 + l];
    float b2 = F[W_O2B];
    #pragma unroll
    for (int rr = 0; rr < 4; ++rr){
        int m = w*4 + rr;
        float s = 0.0f;
        #pragma unroll
        for (int c4 = 0; c4 < 4; ++c4) s += x1[m][c4*64 + l]*w2v[c4];
        for (int off = 32; off > 0; off >>= 1) s += __shfl_xor(s, off, 64);
        if (l == 0){
            float val = s + b2;
            long g = r0 + m;
            if (mode == 0) ((u16*)out)[g] = f2bf(val);
            else           ((float*)out)[g] = val;
        }
    }
    if (blockIdx.x==0 && tid==0) put_sent(ws, 5);
}

// =========================================================================
// checker: writes 400+10*i to out[0] if sentinel i missing
// =========================================================================
__global__ __launch_bounds__(64) void MTANet_7593502179851_kernel(char* ws, void* out)
{
    if (threadIdx.x == 0){
        const unsigned int* sent = (const unsigned int*)(ws+OFF_SENT);
        int mode = *(const int*)(ws+OFF_FLAG);
        for (int i = 0; i < 7; ++i){
            if (sent[i] != (SENT_MAGIC | (unsigned int)i)){
                float code = 400.0f + 10.0f*(float)i;
                if (mode == 0) ((u16*)out)[0] = f2bf(code);
                else           ((float*)out)[0] = code;
                break;
            }
        }
    }
}

__global__ __launch_bounds__(64) void k_diag(void* out, float code)
{
    if (threadIdx.x == 0){
        ((u16*)out)[0] = f2bf(code);
        ((float*)out)[1] = code;
    }
}

// =========================================================================
extern "C" void kernel_launch(void* const* d_in, const int* in_sizes, int n_in,
                              void* d_out, int out_size, void* d_ws, size_t ws_size,
                              hipStream_t stream)
{
    char* ws = (char*)d_ws;

    static const int exp_sizes[18] = {
        4128768, 6144, 98304, 73728, 589824, 2304, 196608, 196608, 768,
        590592, 196608, 768, 4096, 256, 327680, 256, 256, 1 };
    int bad_i = -1;
    if (n_in != 18) bad_i = 99;
    else for (int i = 0; i < 18; ++i)
        if (in_sizes[i] != exp_sizes[i]){ bad_i = i; break; }
    if (bad_i >= 0){
        k_diag<<<dim3(1), dim3(64), 0, stream>>>(d_out, 900.0f + (float)bad_i);
        return;
    }
    if (ws_size < (size_t)NEED_BYTES){
        k_diag<<<dim3(1), dim3(64), 0, stream>>>(d_out, 600.0f);
        return;
    }

    P15 wp;
    for (int i = 0; i < 15; ++i) wp.p[i] = d_in[3+i];

    hipError_t le[12];
    for (int i = 0; i < 12; ++i) le[i] = hipSuccess;
    (void)hipGetLastError();
    #define CHK(slot) { hipError_t e_ = hipGetLastError(); if (e_ != hipSuccess && le[slot] == hipSuccess) le[slot] = e_; }

    k_probe<<<dim3(1), dim3(256), 0, stream>>>((const u16*)d_in[3], ws);       CHK(0)
    k_convert<<<dim3(256,15), dim3(256), 0, stream>>>(wp, ws);                 CHK(1)
    k_pack<<<dim3(1152,8), dim3(64), 0, stream>>>(ws);                         CHK(2)
    k_init<<<dim3(1024), dim3(256), 0, stream>>>(ws);                          CHK(3)
    k_enc<<<dim3(16,3), dim3(256), 0, stream>>>(d_in[0], ws, (u16*)(ws+OFF_ENCOUT)); CHK(4)
    k_proj<<<dim3(1344,3), dim3(256), 0, stream>>>(ws);                        CHK(5)

    float* hbuf0 = (float*)(ws+OFF_H0);
    float* hbuf1 = (float*)(ws+OFF_H1);
    float* h_last = hbuf0;
    for (int s = 0; s < HOR; ++s){
        float* h_in  = (s & 1) ? hbuf1 : hbuf0;
        float* h_out = (s & 1) ? hbuf0 : hbuf1;
        k_dec_gru<<<dim3(16,16), dim3(192), 0, stream>>>(ws, h_in, h_out, d_in[1], s); CHK(6)
        k_q<<<dim3(32,3), dim3(256), 0, stream>>>(ws, h_out);                   CHK(7)
        k_attn<<<dim3(256,3), dim3(256), 0, stream>>>(ws);                      CHK(8)
        h_last = h_out;
    }
    k_head1<<<dim3(32), dim3(256), 0, stream>>>(ws, h_last);                   CHK(9)
    k_ext<<<dim3(96), dim3(256), 0, stream>>>(d_in[2], ws);                    CHK(10)
    k_head2<<<dim3(384), dim3(256), 0, stream>>>(ws, d_out);                   CHK(11)
    MTANet_7593502179851_kernel<<<dim3(1), dim3(64), 0, stream>>>(ws, d_out);
    #undef CHK

    for (int i = 0; i < 12; ++i){
        if (le[i] != hipSuccess){
            k_diag<<<dim3(1), dim3(64), 0, stream>>>(d_out, 800.0f + (float)i);
            break;
        }
    }
}

// Round 7
// 4095.171 us; speedup vs baseline: 4.3098x; 1.7682x over previous
//
#include <hip/hip_runtime.h>
#include <math.h>

typedef unsigned short u16;
typedef float f4v __attribute__((ext_vector_type(4)));
typedef __bf16 bfv8 __attribute__((ext_vector_type(8)));

// gfx950 MFMA: D = A(16x32 bf16) * B(32x16 bf16) + C(f32x4)
#define MFMA16(a,b,c) __builtin_amdgcn_mfma_f32_16x16x32_bf16((a),(b),(c),0,0,0)

// ---------------- numeric helpers ----------------
__device__ __forceinline__ float bf2f(u16 x){
    unsigned int u = ((unsigned int)x) << 16;
    float f; __builtin_memcpy(&f, &u, 4); return f;
}
__device__ __forceinline__ u16 f2bf(float f){
    unsigned int u; __builtin_memcpy(&u, &f, 4);
    u += 0x7fffu + ((u >> 16) & 1u);
    return (u16)(u >> 16);
}
// mode: 0 = bf16 wire, 1 = f32 wire
__device__ __forceinline__ float ldmix(const void* p, long i, int mode){
    if (mode) return ((const float*)p)[i];
    return bf2f(((const u16*)p)[i]);
}
__device__ __forceinline__ float sigf(float x){ return 1.0f/(1.0f+__expf(-x)); }
__device__ __forceinline__ float tanh_fast(float x){
    float e = __expf(2.0f*x);           // inf-safe: x>>0 -> 1, x<<0 -> -1
    return 1.0f - 2.0f/(1.0f+e);
}

// ---------------- sizes ----------------
#define BATCH 256
#define TLEN 168
#define HOR 24

// ---------------- workspace layout (bytes) ----------------
#define OFF_FLAG 0ull
#define OFF_SENT 16ull
#define OFF_WF   256ull          // f32 weights, 2180353 elems
#define OFF_UP   8721920ull      // packed enc_U  3*196608 u16
#define OFF_WP   9901568ull      // packed enc_W  3*24576 u16
#define OFF_DWP  10049024ull     // packed dec_W rows 0..767, 589824 u16
#define OFF_DUP  11228672ull     // packed dec_U 196608 u16
#define OFF_H0   11621888ull     // 65536 f32
#define OFF_H1   11884032ull     // 65536 f32
#define OFF_C    12146176ull     // 196608 f32
#define OFF_Q    12932608ull     // 196608 f32
#define OFF_SP   13719040ull     // 65536 f32
#define OFF_E    13981184ull     // 1572864 u16 (bf16)
#define OFF_ENCOUT 17126912ull   // 33030144 u16
#define OFF_PROJ 83187200ull     // 33030144 u16
#define NEED_BYTES 149247488ull

// f32-element offsets inside the converted-weights region
#define W_ENCW 0
#define W_ENCU 73728
#define W_ENCB 663552
#define W_AW1  665856
#define W_AW2  862464
#define W_AV   1059072
#define W_DECW 1059840
#define W_DECU 1650432
#define W_DECB 1847040
#define W_EXTW 1847808
#define W_EXTB 1851904
#define W_O1W  1852160
#define W_O1B  2179840
#define W_O2W  2180096
#define W_O2B  2180352

__device__ const int c_wsz[15]  = {73728,589824,2304,196608,196608,768,590592,196608,768,4096,256,327680,256,256,1};
__device__ const int c_woff[15] = {W_ENCW,W_ENCU,W_ENCB,W_AW1,W_AW2,W_AV,W_DECW,W_DECU,W_DECB,W_EXTW,W_EXTB,W_O1W,W_O1B,W_O2W,W_O2B};

struct P15 { const void* p[15]; };

#define SENT_MAGIC 0x5AFE0000u
__device__ __forceinline__ void put_sent(char* ws, int idx){
    ((unsigned int*)(ws+OFF_SENT))[idx] = SENT_MAGIC | (unsigned int)idx;
}

// =========================================================================
// probe: decide wire dtype (bf16 reinterpretation of f32 words is huge)
// =========================================================================
__global__ __launch_bounds__(256) void k_probe(const u16* w16, char* ws)
{
    __shared__ float red[256];
    int tid = threadIdx.x;
    float mb = 0.0f;
    for (int i = tid; i < 2048; i += 256){
        float a = fabsf(bf2f(w16[i]));
        if (a > mb) mb = a;
    }
    red[tid] = mb;
    __syncthreads();
    if (tid == 0){
        for (int i = 1; i < 256; ++i) if (red[i] > mb) mb = red[i];
        *(int*)(ws+OFF_FLAG) = (mb > 1000.0f) ? 1 : 0;
        put_sent(ws, 0);
    }
}

// =========================================================================
// convert the 15 weight tensors to f32 in ws
// =========================================================================
__global__ __launch_bounds__(256) void k_convert(P15 in, char* ws)
{
    int mode = *(const int*)(ws+OFF_FLAG);
    float* F = (float*)(ws+OFF_WF);
    int y = blockIdx.y;
    int sz = c_wsz[y], off = c_woff[y];
    for (long i = (long)blockIdx.x*256 + threadIdx.x; i < sz; i += 256L*256L)
        F[off + i] = ldmix(in.p[y], i, mode);
    if (blockIdx.x==0 && blockIdx.y==0 && threadIdx.x==0) put_sent(ws, 1);
}

// =========================================================================
// pack: F(f32 row-major [K][N]) -> bf16 MFMA B-frags (K=32 tiles)
// =========================================================================
__global__ __launch_bounds__(64) void k_pack(char* ws)
{
    const float* F = (const float*)(ws+OFF_WF);
    int m = blockIdx.y;
    const float* src; u16* dst; int K, N;
    switch (m) {
      case 0: case 1: case 2:
        src = F + W_ENCU + m*196608; dst = (u16*)(ws+OFF_UP) + m*196608; K=256; N=768; break;
      case 3: case 4: case 5:
        src = F + W_ENCW + (m-3)*24576; dst = (u16*)(ws+OFF_WP) + (m-3)*24576; K=32; N=768; break;
      case 6:
        src = F + W_DECW; dst = (u16*)(ws+OFF_DWP); K=768; N=768; break;
      default:
        src = F + W_DECU; dst = (u16*)(ws+OFF_DUP); K=256; N=768; break;
    }
    int KT = K>>5, NT = N>>4;
    int tau = blockIdx.x;
    if (tau < KT*NT){
        int ct = tau / KT, kt = tau % KT;
        int l = threadIdx.x, q = l>>4, c = l&15;
        #pragma unroll
        for (int j = 0; j < 8; ++j)
            dst[((size_t)(ct*KT+kt)*64 + l)*8 + j] = f2bf(src[(size_t)(kt*32 + q*8 + j)*N + ct*16 + c]);
    }
    if (blockIdx.x==0 && blockIdx.y==0 && threadIdx.x==0) put_sent(ws, 6);
}

// =========================================================================
__global__ __launch_bounds__(256) void k_init(char* ws)
{
    long idx = (long)blockIdx.x*256 + threadIdx.x;
    if (idx < 65536) ((float*)(ws+OFF_H0))[idx] = 0.0f;
    else ((float*)(ws+OFF_C))[idx-65536] = 0.0f;
}

// =========================================================================
// encoder GRU (MFMA): grid (16 rowtiles16, 3 encs), 512 thr (8 waves).
// Each wave owns 2 column tiles (all 3 gates). Split hi/lo accumulator
// chains: max dependent-MFMA chain = 9 (was ~34) — latency-bound fix.
// =========================================================================
__global__ __launch_bounds__(512) void k_enc(const void* enc_in, char* ws, u16* enc_out)
{
    const float* F = (const float*)(ws+OFF_WF);
    int mode = *(const int*)(ws+OFF_FLAG);
    const int n  = blockIdx.y;
    const int b0 = blockIdx.x*16;
    const int tid = threadIdx.x;
    const int w = tid>>6, l = tid&63, quad = l>>4, c15 = l&15;

    __shared__ __align__(16) u16 hAhi[2][8][64][8];
    __shared__ __align__(16) u16 hAlo[2][8][64][8];
    __shared__ __align__(16) u16 sx[64][8];

    {
        int* z0 = (int*)&hAhi[0][0][0][0];
        int* z1 = (int*)&hAlo[0][0][0][0];
        for (int i = tid; i < 4096; i += 512){ z0[i]=0; z1[i]=0; }
    }
    float h[8];
    #pragma unroll
    for (int i=0;i<8;++i) h[i]=0.0f;

    float bzr[2], brr[2], bnr[2];
    #pragma unroll
    for (int si=0;si<2;++si){
        int u = (w*2+si)*16 + c15;
        bzr[si] = F[W_ENCB + n*768 + u];
        brr[si] = F[W_ENCB + n*768 + 256 + u];
        bnr[si] = F[W_ENCB + n*768 + 512 + u];
    }
    __syncthreads();

    const u16* upn = (const u16*)(ws+OFF_UP) + n*196608;   // KT=8
    const u16* wpn = (const u16*)(ws+OFF_WP) + n*24576;    // KT=1

    for (int t = 0; t < TLEN; ++t){
        int p = t & 1;
        // stage x(t) as one K32 A-frag tile: 512 elems, 1 per thread
        {
            int m = tid>>5, k = tid&31;
            sx[(k>>3)*16 + m][k&7] =
                f2bf(ldmix(enc_in, (((long)(n*BATCH + b0 + m))*TLEN + t)*32 + k, mode));
        }
        __syncthreads();

        bfv8 ah[8], al[8];
        #pragma unroll
        for (int kt=0; kt<8; ++kt){
            ah[kt] = *(const bfv8*)&hAhi[p][kt][l][0];
            al[kt] = *(const bfv8*)&hAlo[p][kt][l][0];
        }
        bfv8 ax = *(const bfv8*)&sx[l][0];

        #pragma unroll
        for (int si=0; si<2; ++si){
            int ct = w*2 + si;
            int ctz = ct, ctr = 16 + ct, ctn = 32 + ct;
            f4v azh = {0.f,0.f,0.f,0.f}, azl = {0.f,0.f,0.f,0.f};
            f4v arh = {0.f,0.f,0.f,0.f}, arl = {0.f,0.f,0.f,0.f};
            f4v anx = {0.f,0.f,0.f,0.f};
            f4v anhh = {0.f,0.f,0.f,0.f}, anhl = {0.f,0.f,0.f,0.f};
            azh = MFMA16(ax, *(const bfv8*)(wpn + ((size_t)ctz*64 + l)*8), azh);
            arh = MFMA16(ax, *(const bfv8*)(wpn + ((size_t)ctr*64 + l)*8), arh);
            anx = MFMA16(ax, *(const bfv8*)(wpn + ((size_t)ctn*64 + l)*8), anx);
            #pragma unroll
            for (int kt=0; kt<8; ++kt){
                bfv8 bb = *(const bfv8*)(upn + ((size_t)(ctz*8+kt)*64 + l)*8);
                azh = MFMA16(ah[kt], bb, azh);
                azl = MFMA16(al[kt], bb, azl);
            }
            #pragma unroll
            for (int kt=0; kt<8; ++kt){
                bfv8 bb = *(const bfv8*)(upn + ((size_t)(ctr*8+kt)*64 + l)*8);
                arh = MFMA16(ah[kt], bb, arh);
                arl = MFMA16(al[kt], bb, arl);
            }
            #pragma unroll
            for (int kt=0; kt<8; ++kt){
                bfv8 bb = *(const bfv8*)(upn + ((size_t)(ctn*8+kt)*64 + l)*8);
                anhh = MFMA16(ah[kt], bb, anhh);
                anhl = MFMA16(al[kt], bb, anhl);
            }
            int u = ct*16 + c15;
            #pragma unroll
            for (int j=0;j<4;++j){
                int m = quad*4 + j;
                float z = sigf(azh[j] + azl[j] + bzr[si]);
                float r = sigf(arh[j] + arl[j] + brr[si]);
                float ng = tanh_fast(anx[j] + bnr[si] + r*(anhh[j] + anhl[j]));
                float hn = (1.0f - z)*h[si*4+j] + z*ng;
                h[si*4+j] = hn;
                enc_out[(((long)(n*BATCH + b0 + m))*TLEN + t)*256 + u] = f2bf(hn);
                u16 hi = f2bf(hn);
                u16 lo = f2bf(hn - bf2f(hi));
                int kt = u>>5, q2 = (u>>3)&3, j2 = u&7;
                hAhi[1-p][kt][q2*16+m][j2] = hi;
                hAlo[1-p][kt][q2*16+m][j2] = lo;
            }
        }
        __syncthreads();
    }
    if (blockIdx.x==0 && blockIdx.y==0 && tid==0) put_sent(ws, 2);
}

// =========================================================================
// proj = enc_out @ att_W1[n] (VALU): grid (1344 rowtiles32, 3), 256 thr
// =========================================================================
__global__ __launch_bounds__(256) void k_proj(char* ws)
{
    const float* F = (const float*)(ws+OFF_WF);
    const u16* enc16 = (const u16*)(ws+OFF_ENCOUT);
    u16* proj = (u16*)(ws+OFF_PROJ);
    const int n = blockIdx.y;
    const long r0 = (long)blockIdx.x*32;
    const int tid = threadIdx.x;

    __shared__ float A[32][256];
    long base = ((long)n*43008 + r0)*256;
    for (int i = tid; i < 8192; i += 256)
        A[i>>8][i&255] = bf2f(enc16[base + i]);
    __syncthreads();

    const float* W1 = F + W_AW1 + n*65536;
    float acc[32];
    #pragma unroll
    for (int r = 0; r < 32; ++r) acc[r] = 0.0f;
    for (int k = 0; k < 256; ++k){
        float w = W1[k*256 + tid];
        #pragma unroll
        for (int r = 0; r < 32; ++r) acc[r] += A[r][k]*w;
    }
    for (int r = 0; r < 32; ++r)
        proj[base + (long)r*256 + tid] = f2bf(acc[r]);
    if (blockIdx.x==0 && blockIdx.y==0 && tid==0) put_sent(ws, 3);
}

// =========================================================================
// decoder GRU step (MFMA, fused gates): grid (16 rowtiles16, 16 u-slices),
// 192 thr (wave = gate). A = [c(768) | h(256)] hi/lo staged in LDS.
// =========================================================================
__global__ __launch_bounds__(192) void k_dec_gru(
    char* ws, const float* h_in, float* h_out, const void* dec_in, int step)
{
    const float* F = (const float*)(ws+OFF_WF);
    const float* C = (const float*)(ws+OFF_C);
    int mode = *(const int*)(ws+OFF_FLAG);
    const u16* dwp = (const u16*)(ws+OFF_DWP);   // KT=24
    const u16* dup = (const u16*)(ws+OFF_DUP);   // KT=8
    const int b0 = blockIdx.x*16;
    const int us = blockIdx.y;
    const int u0 = us*16;
    const int tid = threadIdx.x;
    const int gate = tid>>6, l = tid&63, quad = l>>4, c15 = l&15;
    const int ct = gate*16 + us;

    __shared__ __align__(16) u16 aH[16][64][8];
    __shared__ __align__(16) u16 aL[16][64][8];
    __shared__ float gz[16][16], gr[16][16], gx[16][16], gh[16][16];

    f4v accA = {0.f,0.f,0.f,0.f};
    f4v accAl = {0.f,0.f,0.f,0.f};
    f4v accB = {0.f,0.f,0.f,0.f};
    f4v accBl = {0.f,0.f,0.f,0.f};

    for (int half = 0; half < 2; ++half){
        __syncthreads();
        for (int e = tid; e < 8192; e += 192){
            int m = e>>9, kk = e&511;
            int kg = half*512 + kk;
            float v = (kg < 768) ? C[(long)(b0+m)*768 + kg]
                                 : h_in[(long)(b0+m)*256 + kg - 768];
            u16 hi = f2bf(v);
            u16 lo = f2bf(v - bf2f(hi));
            int ktl = kk>>5, q2 = (kk>>3)&3, j2 = kk&7;
            aH[ktl][q2*16+m][j2] = hi;
            aL[ktl][q2*16+m][j2] = lo;
        }
        __syncthreads();
        #pragma unroll
        for (int ktl = 0; ktl < 16; ++ktl){
            int kg = half*16 + ktl;
            const u16* bp = (kg < 24) ? dwp + ((size_t)(ct*24 + kg)*64 + l)*8
                                      : dup + ((size_t)(ct*8  + (kg-24))*64 + l)*8;
            bfv8 bb = *(const bfv8*)bp;
            bfv8 ah = *(const bfv8*)&aH[ktl][l][0];
            bfv8 al = *(const bfv8*)&aL[ktl][l][0];
            if (gate == 2 && kg >= 24){
                accB  = MFMA16(ah, bb, accB);
                accBl = MFMA16(al, bb, accBl);
            } else {
                accA  = MFMA16(ah, bb, accA);
                accAl = MFMA16(al, bb, accAl);
            }
        }
    }
    #pragma unroll
    for (int j=0;j<4;++j){
        int m = quad*4 + j;
        float va = accA[j] + accAl[j];
        float vb = accB[j] + accBl[j];
        if (gate == 0) gz[m][c15] = va;
        else if (gate == 1) gr[m][c15] = va;
        else { gx[m][c15] = va; gh[m][c15] = vb; }
    }
    __syncthreads();
    for (int e = tid; e < 256; e += 192){
        int m = e>>4, j = e&15;
        int u = u0 + j;
        int b = b0 + m;
        float db = ldmix(dec_in, (long)b*HOR + step, mode);
        float sz = gz[m][j] + db*F[W_DECW + 768*768 + u]       + F[W_DECB + u];
        float sr = gr[m][j] + db*F[W_DECW + 768*768 + 256 + u] + F[W_DECB + 256 + u];
        float sn = gx[m][j] + db*F[W_DECW + 768*768 + 512 + u] + F[W_DECB + 512 + u];
        float z = sigf(sz);
        float r = sigf(sr);
        float ng = tanh_fast(sn + r*gh[m][j]);
        h_out[(long)b*256 + u] = (1.0f - z)*h_in[(long)b*256 + u] + z*ng;
    }
}

// =========================================================================
// q[n] = h @ att_W2[n] (VALU): grid (32 rowtiles8, 3), 256 thr
// =========================================================================
__global__ __launch_bounds__(256) void k_q(char* ws, const float* h)
{
    const float* F = (const float*)(ws+OFF_WF);
    float* Q = (float*)(ws+OFF_Q);
    const int n = blockIdx.y;
    const int b0 = blockIdx.x*8;
    const int tid = threadIdx.x;

    __shared__ float A[8][256];
    for (int i = tid; i < 2048; i += 256)
        A[i>>8][i&255] = h[(long)b0*256 + i];
    __syncthreads();

    const float* W2 = F + W_AW2 + n*65536;
    float acc[8];
    #pragma unroll
    for (int r = 0; r < 8; ++r) acc[r] = 0.0f;
    for (int k = 0; k < 256; ++k){
        float w = W2[k*256 + tid];
        #pragma unroll
        for (int r = 0; r < 8; ++r) acc[r] += A[r][k]*w;
    }
    for (int r = 0; r < 8; ++r)
        Q[(long)(n*BATCH + b0 + r)*256 + tid] = acc[r];
}

// =========================================================================
// attention: grid (256 b, 3 n), 256 thr. LDS-partial design — no dependent
// shuffle chains; fully pipelined loads.
// =========================================================================
__global__ __launch_bounds__(256) void k_attn(char* ws)
{
    const float* F = (const float*)(ws+OFF_WF);
    const float* Q = (const float*)(ws+OFF_Q);
    const u16* proj = (const u16*)(ws+OFF_PROJ);
    const u16* enc16 = (const u16*)(ws+OFF_ENCOUT);
    float* C = (float*)(ws+OFF_C);
    const int b = blockIdx.x, n = blockIdx.y;
    const int tid = threadIdx.x;
    const int w = tid>>6, l = tid&63;

    __shared__ float ps[TLEN][65];   // per-lane score partials (padded)
    __shared__ float sc[TLEN];

    float qv[4], vv[4];
    #pragma unroll
    for (int c4 = 0; c4 < 4; ++c4){
        qv[c4] = Q[(long)(n*BATCH + b)*256 + c4*64 + l];
        vv[c4] = F[W_AV + n*256 + c4*64 + l];
    }
    long base = ((long)n*43008 + (long)b*TLEN)*256;
    const u16* pb = proj + base;

    // phase 1: independent per-(t,lane) partials
    for (int i = 0; i < 42; ++i){
        int t = w*42 + i;
        float s = 0.0f;
        #pragma unroll
        for (int c4 = 0; c4 < 4; ++c4){
            float pv = bf2f(pb[(long)t*256 + c4*64 + l]);
            s += vv[c4]*tanh_fast(pv + qv[c4]);
        }
        ps[t][l] = s;
    }
    __syncthreads();
    // phase 2: per-t reduce across 64 lanes (padded stride: conflict-free)
    if (tid < TLEN){
        float s0 = 0.0f, s1 = 0.0f;
        for (int j = 0; j < 64; j += 2){
            s0 += ps[tid][j];
            s1 += ps[tid][j+1];
        }
        sc[tid] = s0 + s1;
    }
    __syncthreads();
    float mx = -1e30f;
    for (int t = 0; t < TLEN; ++t) if (sc[t] > mx) mx = sc[t];
    __syncthreads();
    if (tid < TLEN) sc[tid] = __expf(sc[tid]-mx);
    __syncthreads();
    float sum = 0.0f;
    for (int t = 0; t < TLEN; ++t) sum += sc[t];
    float inv = 1.0f/sum;
    // ctx: 4 independent accumulator chains
    const u16* eb = enc16 + base;
    float a0=0.f, a1=0.f, a2=0.f, a3=0.f;
    for (int t = 0; t < TLEN; t += 4){
        a0 += sc[t  ]*bf2f(eb[(long)(t  )*256 + tid]);
        a1 += sc[t+1]*bf2f(eb[(long)(t+1)*256 + tid]);
        a2 += sc[t+2]*bf2f(eb[(long)(t+2)*256 + tid]);
        a3 += sc[t+3]*bf2f(eb[(long)(t+3)*256 + tid]);
    }
    C[(long)b*768 + n*256 + tid] = (a0+a1+a2+a3)*inv;
    if (b==0 && n==0 && tid==0) put_sent(ws, 4);
}

// =========================================================================
// head1: sp = [h,c] @ out1_W[0:1024] : grid 32 rowtiles8, 256 thr
// =========================================================================
__global__ __launch_bounds__(256) void k_head1(char* ws, const float* h_last)
{
    const float* F = (const float*)(ws+OFF_WF);
    const float* C = (const float*)(ws+OFF_C);
    float* SP = (float*)(ws+OFF_SP);
    const int b0 = blockIdx.x*8;
    const int tid = threadIdx.x;

    __shared__ float A[8][1024];
    for (int i = tid; i < 8192; i += 256){
        int r = i >> 10, k = i & 1023;
        A[r][k] = (k < 256) ? h_last[(long)(b0+r)*256 + k]
                            : C[(long)(b0+r)*768 + (k-256)];
    }
    __syncthreads();

    const float* W = F + W_O1W;
    float acc[8];
    float bc = F[W_O1B + tid];
    #pragma unroll
    for (int r = 0; r < 8; ++r) acc[r] = bc;
    for (int k = 0; k < 1024; ++k){
        float w = W[k*256 + tid];
        #pragma unroll
        for (int r = 0; r < 8; ++r) acc[r] += A[r][k]*w;
    }
    for (int r = 0; r < 8; ++r)
        SP[(long)(b0+r)*256 + tid] = acc[r];
}

// =========================================================================
// ext: E = relu(ext_feat @ ext_W + ext_b) -> bf16 : grid 96, 256 thr
// =========================================================================
__global__ __launch_bounds__(256) void k_ext(const void* ext_feat, char* ws)
{
    const float* F = (const float*)(ws+OFF_WF);
    u16* E = (u16*)(ws+OFF_E);
    int mode = *(const int*)(ws+OFF_FLAG);
    const int r0 = blockIdx.x*64;
    const int tid = threadIdx.x;
    __shared__ float ef[64][16];
    for (int i = tid; i < 1024; i += 256)
        ef[i>>4][i&15] = ldmix(ext_feat, (long)(r0 + (i>>4))*16 + (i&15), mode);
    float wreg[16];
    #pragma unroll
    for (int k = 0; k < 16; ++k) wreg[k] = F[W_EXTW + k*256 + tid];
    float bb = F[W_EXTB + tid];
    __syncthreads();
    for (int r = 0; r < 64; ++r){
        float a = bb;
        #pragma unroll
        for (int k = 0; k < 16; ++k) a += ef[r][k]*wreg[k];
        E[(long)(r0+r)*256 + tid] = f2bf((a > 0.0f) ? a : 0.0f);
    }
}

// =========================================================================
// head2: x1 = relu(sp[b] + E@out1_W[1024:] + b1); out = x1@out2_W + b2
// =========================================================================
__global__ __launch_bounds__(256) void k_head2(char* ws, void* out)
{
    const float* F = (const float*)(ws+OFF_WF);
    const u16* E = (const u16*)(ws+OFF_E);
    const float* SP = (const float*)(ws+OFF_SP);
    int mode = *(const int*)(ws+OFF_FLAG);
    const int r0 = blockIdx.x*16;
    const int tid = threadIdx.x;
    const int w = tid>>6, l = tid&63;

    __shared__ float A[16][256];
    __shared__ float x1[16][257];
    for (int i = tid; i < 4096; i += 256)
        A[i>>8][i&255] = bf2f(E[(long)r0*256 + i]);
    __syncthreads();

    const float* W = F + W_O1W + 1024*256;
    float acc[16];
    float bc = F[W_O1B + tid];
    #pragma unroll
    for (int r = 0; r < 16; ++r) acc[r] = 0.0f;
    for (int k = 0; k < 256; ++k){
        float wv = W[k*256 + tid];
        #pragma unroll
        for (int r = 0; r < 16; ++r) acc[r] += A[r][k]*wv;
    }
    for (int r = 0; r < 16; ++r){
        int g = r0 + r;
        int b = g / HOR;
        float v = acc[r] + SP[(long)b*256 + tid] + bc;
        x1[r][tid] = (v > 0.0f) ? v : 0.0f;
    }
    __syncthreads();

    float w2v[4];
    #pragma unroll
    for (int c4 = 0; c4 < 4; ++c4) w2v[c4] = F[W_O2W + c4*64 + l];
    float b2 = F[W_O2B];
    #pragma unroll
    for (int rr = 0; rr < 4; ++rr){
        int m = w*4 + rr;
        float s = 0.0f;
        #pragma unroll
        for (int c4 = 0; c4 < 4; ++c4) s += x1[m][c4*64 + l]*w2v[c4];
        for (int off = 32; off > 0; off >>= 1) s += __shfl_xor(s, off, 64);
        if (l == 0){
            float val = s + b2;
            long g = r0 + m;
            if (mode == 0) ((u16*)out)[g] = f2bf(val);
            else           ((float*)out)[g] = val;
        }
    }
    if (blockIdx.x==0 && tid==0) put_sent(ws, 5);
}

// =========================================================================
// checker: writes 400+10*i to out[0] if sentinel i missing
// =========================================================================
__global__ __launch_bounds__(64) void MTANet_7593502179851_kernel(char* ws, void* out)
{
    if (threadIdx.x == 0){
        const unsigned int* sent = (const unsigned int*)(ws+OFF_SENT);
        int mode = *(const int*)(ws+OFF_FLAG);
        for (int i = 0; i < 7; ++i){
            if (sent[i] != (SENT_MAGIC | (unsigned int)i)){
                float code = 400.0f + 10.0f*(float)i;
                if (mode == 0) ((u16*)out)[0] = f2bf(code);
                else           ((float*)out)[0] = code;
                break;
            }
        }
    }
}

__global__ __launch_bounds__(64) void k_diag(void* out, float code)
{
    if (threadIdx.x == 0){
        ((u16*)out)[0] = f2bf(code);
        ((float*)out)[1] = code;
    }
}

// =========================================================================
extern "C" void kernel_launch(void* const* d_in, const int* in_sizes, int n_in,
                              void* d_out, int out_size, void* d_ws, size_t ws_size,
                              hipStream_t stream)
{
    char* ws = (char*)d_ws;

    static const int exp_sizes[18] = {
        4128768, 6144, 98304, 73728, 589824, 2304, 196608, 196608, 768,
        590592, 196608, 768, 4096, 256, 327680, 256, 256, 1 };
    int bad_i = -1;
    if (n_in != 18) bad_i = 99;
    else for (int i = 0; i < 18; ++i)
        if (in_sizes[i] != exp_sizes[i]){ bad_i = i; break; }
    if (bad_i >= 0){
        k_diag<<<dim3(1), dim3(64), 0, stream>>>(d_out, 900.0f + (float)bad_i);
        return;
    }
    if (ws_size < (size_t)NEED_BYTES){
        k_diag<<<dim3(1), dim3(64), 0, stream>>>(d_out, 600.0f);
        return;
    }

    P15 wp;
    for (int i = 0; i < 15; ++i) wp.p[i] = d_in[3+i];

    hipError_t le[12];
    for (int i = 0; i < 12; ++i) le[i] = hipSuccess;
    (void)hipGetLastError();
    #define CHK(slot) { hipError_t e_ = hipGetLastError(); if (e_ != hipSuccess && le[slot] == hipSuccess) le[slot] = e_; }

    k_probe<<<dim3(1), dim3(256), 0, stream>>>((const u16*)d_in[3], ws);       CHK(0)
    k_convert<<<dim3(256,15), dim3(256), 0, stream>>>(wp, ws);                 CHK(1)
    k_pack<<<dim3(1152,8), dim3(64), 0, stream>>>(ws);                         CHK(2)
    k_init<<<dim3(1024), dim3(256), 0, stream>>>(ws);                          CHK(3)
    k_enc<<<dim3(16,3), dim3(512), 0, stream>>>(d_in[0], ws, (u16*)(ws+OFF_ENCOUT)); CHK(4)
    k_proj<<<dim3(1344,3), dim3(256), 0, stream>>>(ws);                        CHK(5)

    float* hbuf0 = (float*)(ws+OFF_H0);
    float* hbuf1 = (float*)(ws+OFF_H1);
    float* h_last = hbuf0;
    for (int s = 0; s < HOR; ++s){
        float* h_in  = (s & 1) ? hbuf1 : hbuf0;
        float* h_out = (s & 1) ? hbuf0 : hbuf1;
        k_dec_gru<<<dim3(16,16), dim3(192), 0, stream>>>(ws, h_in, h_out, d_in[1], s); CHK(6)
        k_q<<<dim3(32,3), dim3(256), 0, stream>>>(ws, h_out);                   CHK(7)
        k_attn<<<dim3(256,3), dim3(256), 0, stream>>>(ws);                      CHK(8)
        h_last = h_out;
    }
    k_head1<<<dim3(32), dim3(256), 0, stream>>>(ws, h_last);                   CHK(9)
    k_ext<<<dim3(96), dim3(256), 0, stream>>>(d_in[2], ws);                    CHK(10)
    k_head2<<<dim3(384), dim3(256), 0, stream>>>(ws, d_out);                   CHK(11)
    MTANet_7593502179851_kernel<<<dim3(1), dim3(64), 0, stream>>>(ws, d_out);
    #undef CHK

    for (int i = 0; i < 12; ++i){
        if (le[i] != hipSuccess){
            k_diag<<<dim3(1), dim3(64), 0, stream>>>(d_out, 800.0f + (float)i);
            break;
        }
    }
}

// Round 9
// 3502.853 us; speedup vs baseline: 5.0386x; 1.1691x over previous
//
#include <hip/hip_runtime.h>
#include <math.h>

typedef unsigned short u16;
typedef float f4v __attribute__((ext_vector_type(4)));
typedef __bf16 bfv8 __attribute__((ext_vector_type(8)));

// gfx950 MFMA: D = A(16x32 bf16) * B(32x16 bf16) + C(f32x4)
#define MFMA16(a,b,c) __builtin_amdgcn_mfma_f32_16x16x32_bf16((a),(b),(c),0,0,0)

// ---------------- numeric helpers ----------------
__device__ __forceinline__ float bf2f(u16 x){
    unsigned int u = ((unsigned int)x) << 16;
    float f; __builtin_memcpy(&f, &u, 4); return f;
}
__device__ __forceinline__ u16 f2bf(float f){
    unsigned int u; __builtin_memcpy(&u, &f, 4);
    u += 0x7fffu + ((u >> 16) & 1u);
    return (u16)(u >> 16);
}
// mode: 0 = bf16 wire, 1 = f32 wire
__device__ __forceinline__ float ldmix(const void* p, long i, int mode){
    if (mode) return ((const float*)p)[i];
    return bf2f(((const u16*)p)[i]);
}
__device__ __forceinline__ float sigf(float x){ return 1.0f/(1.0f+__expf(-x)); }
__device__ __forceinline__ float tanh_fast(float x){
    float e = __expf(2.0f*x);
    return 1.0f - 2.0f/(1.0f+e);
}

// ---------------- sizes ----------------
#define BATCH 256
#define TLEN 168
#define HOR 24

// ---------------- workspace layout (bytes) ----------------
#define OFF_FLAG 0ull
#define OFF_SENT 16ull
#define OFF_WF   256ull          // f32 weights, 2180353 elems
#define OFF_UP   8721920ull      // packed enc_U  3*196608 u16
#define OFF_WP   9901568ull      // packed enc_W  3*24576 u16
#define OFF_DWP  10049024ull     // packed dec_W rows 0..767, 589824 u16
#define OFF_DUP  11228672ull     // packed dec_U 196608 u16
#define OFF_H0   11621888ull     // 65536 f32
#define OFF_H1   11884032ull     // 65536 f32
#define OFF_C    12146176ull     // 196608 f32
#define OFF_Q    12932608ull     // 196608 f32
#define OFF_SP   13719040ull     // 65536 f32
#define OFF_E    13981184ull     // 1572864 u16 (bf16)
#define OFF_ENCOUT 17126912ull   // 33030144 u16
#define OFF_PROJ 83187200ull     // 33030144 u16
#define NEED_BYTES 149247488ull

// f32-element offsets inside the converted-weights region
#define W_ENCW 0
#define W_ENCU 73728
#define W_ENCB 663552
#define W_AW1  665856
#define W_AW2  862464
#define W_AV   1059072
#define W_DECW 1059840
#define W_DECU 1650432
#define W_DECB 1847040
#define W_EXTW 1847808
#define W_EXTB 1851904
#define W_O1W  1852160
#define W_O1B  2179840
#define W_O2W  2180096
#define W_O2B  2180352

__device__ const int c_wsz[15]  = {73728,589824,2304,196608,196608,768,590592,196608,768,4096,256,327680,256,256,1};
__device__ const int c_woff[15] = {W_ENCW,W_ENCU,W_ENCB,W_AW1,W_AW2,W_AV,W_DECW,W_DECU,W_DECB,W_EXTW,W_EXTB,W_O1W,W_O1B,W_O2W,W_O2B};

struct P15 { const void* p[15]; };

#define SENT_MAGIC 0x5AFE0000u
__device__ __forceinline__ void put_sent(char* ws, int idx){
    ((unsigned int*)(ws+OFF_SENT))[idx] = SENT_MAGIC | (unsigned int)idx;
}

// =========================================================================
// probe: decide wire dtype
// =========================================================================
__global__ __launch_bounds__(256) void k_probe(const u16* w16, char* ws)
{
    __shared__ float red[256];
    int tid = threadIdx.x;
    float mb = 0.0f;
    for (int i = tid; i < 2048; i += 256){
        float a = fabsf(bf2f(w16[i]));
        if (a > mb) mb = a;
    }
    red[tid] = mb;
    __syncthreads();
    if (tid == 0){
        for (int i = 1; i < 256; ++i) if (red[i] > mb) mb = red[i];
        *(int*)(ws+OFF_FLAG) = (mb > 1000.0f) ? 1 : 0;
        put_sent(ws, 0);
    }
}

// =========================================================================
// convert the 15 weight tensors to f32 in ws
// =========================================================================
__global__ __launch_bounds__(256) void k_convert(P15 in, char* ws)
{
    int mode = *(const int*)(ws+OFF_FLAG);
    float* F = (float*)(ws+OFF_WF);
    int y = blockIdx.y;
    int sz = c_wsz[y], off = c_woff[y];
    for (long i = (long)blockIdx.x*256 + threadIdx.x; i < sz; i += 256L*256L)
        F[off + i] = ldmix(in.p[y], i, mode);
    if (blockIdx.x==0 && blockIdx.y==0 && threadIdx.x==0) put_sent(ws, 1);
}

// =========================================================================
// pack: F(f32 row-major [K][N]) -> bf16 MFMA B-frags (K=32 tiles)
// =========================================================================
__global__ __launch_bounds__(64) void k_pack(char* ws)
{
    const float* F = (const float*)(ws+OFF_WF);
    int m = blockIdx.y;
    const float* src; u16* dst; int K, N;
    switch (m) {
      case 0: case 1: case 2:
        src = F + W_ENCU + m*196608; dst = (u16*)(ws+OFF_UP) + m*196608; K=256; N=768; break;
      case 3: case 4: case 5:
        src = F + W_ENCW + (m-3)*24576; dst = (u16*)(ws+OFF_WP) + (m-3)*24576; K=32; N=768; break;
      case 6:
        src = F + W_DECW; dst = (u16*)(ws+OFF_DWP); K=768; N=768; break;
      default:
        src = F + W_DECU; dst = (u16*)(ws+OFF_DUP); K=256; N=768; break;
    }
    int KT = K>>5, NT = N>>4;
    int tau = blockIdx.x;
    if (tau < KT*NT){
        int ct = tau / KT, kt = tau % KT;
        int l = threadIdx.x, q = l>>4, c = l&15;
        #pragma unroll
        for (int j = 0; j < 8; ++j)
            dst[((size_t)(ct*KT+kt)*64 + l)*8 + j] = f2bf(src[(size_t)(kt*32 + q*8 + j)*N + ct*16 + c]);
    }
    if (blockIdx.x==0 && blockIdx.y==0 && threadIdx.x==0) put_sent(ws, 6);
}

// =========================================================================
__global__ __launch_bounds__(256) void k_init(char* ws)
{
    long idx = (long)blockIdx.x*256 + threadIdx.x;
    if (idx < 65536) ((float*)(ws+OFF_H0))[idx] = 0.0f;
    else ((float*)(ws+OFF_C))[idx-65536] = 0.0f;
}

// =========================================================================
// encoder GRU (MFMA): grid (16 rowtiles16, 3 encs), 512 thr (8 waves).
// Split hi/lo accumulator chains. (round-7 proven version, unchanged)
// =========================================================================
__global__ __launch_bounds__(512) void k_enc(const void* enc_in, char* ws, u16* enc_out)
{
    const float* F = (const float*)(ws+OFF_WF);
    int mode = *(const int*)(ws+OFF_FLAG);
    const int n  = blockIdx.y;
    const int b0 = blockIdx.x*16;
    const int tid = threadIdx.x;
    const int w = tid>>6, l = tid&63, quad = l>>4, c15 = l&15;

    __shared__ __align__(16) u16 hAhi[2][8][64][8];
    __shared__ __align__(16) u16 hAlo[2][8][64][8];
    __shared__ __align__(16) u16 sx[64][8];

    {
        int* z0 = (int*)&hAhi[0][0][0][0];
        int* z1 = (int*)&hAlo[0][0][0][0];
        for (int i = tid; i < 4096; i += 512){ z0[i]=0; z1[i]=0; }
    }
    float h[8];
    #pragma unroll
    for (int i=0;i<8;++i) h[i]=0.0f;

    float bzr[2], brr[2], bnr[2];
    #pragma unroll
    for (int si=0;si<2;++si){
        int u = (w*2+si)*16 + c15;
        bzr[si] = F[W_ENCB + n*768 + u];
        brr[si] = F[W_ENCB + n*768 + 256 + u];
        bnr[si] = F[W_ENCB + n*768 + 512 + u];
    }
    __syncthreads();

    const u16* upn = (const u16*)(ws+OFF_UP) + n*196608;   // KT=8
    const u16* wpn = (const u16*)(ws+OFF_WP) + n*24576;    // KT=1

    for (int t = 0; t < TLEN; ++t){
        int p = t & 1;
        {
            int m = tid>>5, k = tid&31;
            sx[(k>>3)*16 + m][k&7] =
                f2bf(ldmix(enc_in, (((long)(n*BATCH + b0 + m))*TLEN + t)*32 + k, mode));
        }
        __syncthreads();

        bfv8 ah[8], al[8];
        #pragma unroll
        for (int kt=0; kt<8; ++kt){
            ah[kt] = *(const bfv8*)&hAhi[p][kt][l][0];
            al[kt] = *(const bfv8*)&hAlo[p][kt][l][0];
        }
        bfv8 ax = *(const bfv8*)&sx[l][0];

        #pragma unroll
        for (int si=0; si<2; ++si){
            int ct = w*2 + si;
            int ctz = ct, ctr = 16 + ct, ctn = 32 + ct;
            f4v azh = {0.f,0.f,0.f,0.f}, azl = {0.f,0.f,0.f,0.f};
            f4v arh = {0.f,0.f,0.f,0.f}, arl = {0.f,0.f,0.f,0.f};
            f4v anx = {0.f,0.f,0.f,0.f};
            f4v anhh = {0.f,0.f,0.f,0.f}, anhl = {0.f,0.f,0.f,0.f};
            azh = MFMA16(ax, *(const bfv8*)(wpn + ((size_t)ctz*64 + l)*8), azh);
            arh = MFMA16(ax, *(const bfv8*)(wpn + ((size_t)ctr*64 + l)*8), arh);
            anx = MFMA16(ax, *(const bfv8*)(wpn + ((size_t)ctn*64 + l)*8), anx);
            #pragma unroll
            for (int kt=0; kt<8; ++kt){
                bfv8 bb = *(const bfv8*)(upn + ((size_t)(ctz*8+kt)*64 + l)*8);
                azh = MFMA16(ah[kt], bb, azh);
                azl = MFMA16(al[kt], bb, azl);
            }
            #pragma unroll
            for (int kt=0; kt<8; ++kt){
                bfv8 bb = *(const bfv8*)(upn + ((size_t)(ctr*8+kt)*64 + l)*8);
                arh = MFMA16(ah[kt], bb, arh);
                arl = MFMA16(al[kt], bb, arl);
            }
            #pragma unroll
            for (int kt=0; kt<8; ++kt){
                bfv8 bb = *(const bfv8*)(upn + ((size_t)(ctn*8+kt)*64 + l)*8);
                anhh = MFMA16(ah[kt], bb, anhh);
                anhl = MFMA16(al[kt], bb, anhl);
            }
            int u = ct*16 + c15;
            #pragma unroll
            for (int j=0;j<4;++j){
                int m = quad*4 + j;
                float z = sigf(azh[j] + azl[j] + bzr[si]);
                float r = sigf(arh[j] + arl[j] + brr[si]);
                float ng = tanh_fast(anx[j] + bnr[si] + r*(anhh[j] + anhl[j]));
                float hn = (1.0f - z)*h[si*4+j] + z*ng;
                h[si*4+j] = hn;
                enc_out[(((long)(n*BATCH + b0 + m))*TLEN + t)*256 + u] = f2bf(hn);
                u16 hi = f2bf(hn);
                u16 lo = f2bf(hn - bf2f(hi));
                int kt = u>>5, q2 = (u>>3)&3, j2 = u&7;
                hAhi[1-p][kt][q2*16+m][j2] = hi;
                hAlo[1-p][kt][q2*16+m][j2] = lo;
            }
        }
        __syncthreads();
    }
    if (blockIdx.x==0 && blockIdx.y==0 && tid==0) put_sent(ws, 2);
}

// =========================================================================
// proj = enc_out @ att_W1[n] (VALU): grid (1344 rowtiles32, 3), 256 thr
// =========================================================================
__global__ __launch_bounds__(256) void k_proj(char* ws)
{
    const float* F = (const float*)(ws+OFF_WF);
    const u16* enc16 = (const u16*)(ws+OFF_ENCOUT);
    u16* proj = (u16*)(ws+OFF_PROJ);
    const int n = blockIdx.y;
    const long r0 = (long)blockIdx.x*32;
    const int tid = threadIdx.x;

    __shared__ float A[32][256];
    long base = ((long)n*43008 + r0)*256;
    for (int i = tid; i < 8192; i += 256)
        A[i>>8][i&255] = bf2f(enc16[base + i]);
    __syncthreads();

    const float* W1 = F + W_AW1 + n*65536;
    float acc[32];
    #pragma unroll
    for (int r = 0; r < 32; ++r) acc[r] = 0.0f;
    for (int k = 0; k < 256; ++k){
        float w = W1[k*256 + tid];
        #pragma unroll
        for (int r = 0; r < 32; ++r) acc[r] += A[r][k]*w;
    }
    for (int r = 0; r < 32; ++r)
        proj[base + (long)r*256 + tid] = f2bf(acc[r]);
    if (blockIdx.x==0 && blockIdx.y==0 && tid==0) put_sent(ws, 3);
}

// =========================================================================
// decoder GRU step (MFMA, fused gates): grid (16 rowtiles16, 16 u-slices),
// 192 thr (wave = gate). (round-7 proven version, unchanged)
// =========================================================================
__global__ __launch_bounds__(192) void k_dec_gru(
    char* ws, const float* h_in, float* h_out, const void* dec_in, int step)
{
    const float* F = (const float*)(ws+OFF_WF);
    const float* C = (const float*)(ws+OFF_C);
    int mode = *(const int*)(ws+OFF_FLAG);
    const u16* dwp = (const u16*)(ws+OFF_DWP);   // KT=24
    const u16* dup = (const u16*)(ws+OFF_DUP);   // KT=8
    const int b0 = blockIdx.x*16;
    const int us = blockIdx.y;
    const int u0 = us*16;
    const int tid = threadIdx.x;
    const int gate = tid>>6, l = tid&63, quad = l>>4, c15 = l&15;
    const int ct = gate*16 + us;

    __shared__ __align__(16) u16 aH[16][64][8];
    __shared__ __align__(16) u16 aL[16][64][8];
    __shared__ float gz[16][16], gr[16][16], gx[16][16], gh[16][16];

    f4v accA = {0.f,0.f,0.f,0.f};
    f4v accAl = {0.f,0.f,0.f,0.f};
    f4v accB = {0.f,0.f,0.f,0.f};
    f4v accBl = {0.f,0.f,0.f,0.f};

    for (int half = 0; half < 2; ++half){
        __syncthreads();
        for (int e = tid; e < 8192; e += 192){
            int m = e>>9, kk = e&511;
            int kg = half*512 + kk;
            float v = (kg < 768) ? C[(long)(b0+m)*768 + kg]
                                 : h_in[(long)(b0+m)*256 + kg - 768];
            u16 hi = f2bf(v);
            u16 lo = f2bf(v - bf2f(hi));
            int ktl = kk>>5, q2 = (kk>>3)&3, j2 = kk&7;
            aH[ktl][q2*16+m][j2] = hi;
            aL[ktl][q2*16+m][j2] = lo;
        }
        __syncthreads();
        #pragma unroll
        for (int ktl = 0; ktl < 16; ++ktl){
            int kg = half*16 + ktl;
            const u16* bp = (kg < 24) ? dwp + ((size_t)(ct*24 + kg)*64 + l)*8
                                      : dup + ((size_t)(ct*8  + (kg-24))*64 + l)*8;
            bfv8 bb = *(const bfv8*)bp;
            bfv8 ah = *(const bfv8*)&aH[ktl][l][0];
            bfv8 al = *(const bfv8*)&aL[ktl][l][0];
            if (gate == 2 && kg >= 24){
                accB  = MFMA16(ah, bb, accB);
                accBl = MFMA16(al, bb, accBl);
            } else {
                accA  = MFMA16(ah, bb, accA);
                accAl = MFMA16(al, bb, accAl);
            }
        }
    }
    #pragma unroll
    for (int j=0;j<4;++j){
        int m = quad*4 + j;
        float va = accA[j] + accAl[j];
        float vb = accB[j] + accBl[j];
        if (gate == 0) gz[m][c15] = va;
        else if (gate == 1) gr[m][c15] = va;
        else { gx[m][c15] = va; gh[m][c15] = vb; }
    }
    __syncthreads();
    for (int e = tid; e < 256; e += 192){
        int m = e>>4, j = e&15;
        int u = u0 + j;
        int b = b0 + m;
        float db = ldmix(dec_in, (long)b*HOR + step, mode);
        float sz = gz[m][j] + db*F[W_DECW + 768*768 + u]       + F[W_DECB + u];
        float sr = gr[m][j] + db*F[W_DECW + 768*768 + 256 + u] + F[W_DECB + 256 + u];
        float sn = gx[m][j] + db*F[W_DECW + 768*768 + 512 + u] + F[W_DECB + 512 + u];
        float z = sigf(sz);
        float r = sigf(sr);
        float ng = tanh_fast(sn + r*gh[m][j]);
        h_out[(long)b*256 + u] = (1.0f - z)*h_in[(long)b*256 + u] + z*ng;
    }
}

// =========================================================================
// q[n] = h @ att_W2[n] (VALU): grid (32 rowtiles8, 3), 256 thr
// =========================================================================
__global__ __launch_bounds__(256) void k_q(char* ws, const float* h)
{
    const float* F = (const float*)(ws+OFF_WF);
    float* Q = (float*)(ws+OFF_Q);
    const int n = blockIdx.y;
    const int b0 = blockIdx.x*8;
    const int tid = threadIdx.x;

    __shared__ float A[8][256];
    for (int i = tid; i < 2048; i += 256)
        A[i>>8][i&255] = h[(long)b0*256 + i];
    __syncthreads();

    const float* W2 = F + W_AW2 + n*65536;
    float acc[8];
    #pragma unroll
    for (int r = 0; r < 8; ++r) acc[r] = 0.0f;
    for (int k = 0; k < 256; ++k){
        float w = W2[k*256 + tid];
        #pragma unroll
        for (int r = 0; r < 8; ++r) acc[r] += A[r][k]*w;
    }
    for (int r = 0; r < 8; ++r)
        Q[(long)(n*BATCH + b0 + r)*256 + tid] = acc[r];
}

// =========================================================================
// attention v2: grid (256 b, 3 n), 256 thr. ALL reductions parallel:
// ps-partials (8-chain lane-sum), butterfly shuffle max/sum, 8-way ILP ctx.
// =========================================================================
__global__ __launch_bounds__(256) void k_attn(char* ws)
{
    const float* F = (const float*)(ws+OFF_WF);
    const float* Q = (const float*)(ws+OFF_Q);
    const u16* proj = (const u16*)(ws+OFF_PROJ);
    const u16* enc16 = (const u16*)(ws+OFF_ENCOUT);
    float* C = (float*)(ws+OFF_C);
    const int b = blockIdx.x, n = blockIdx.y;
    const int tid = threadIdx.x;
    const int w = tid>>6, l = tid&63;

    __shared__ float ps[TLEN][65];
    __shared__ float sc[TLEN];
    __shared__ float red[8];

    float qv[4], vv[4];
    #pragma unroll
    for (int c4 = 0; c4 < 4; ++c4){
        qv[c4] = Q[(long)(n*BATCH + b)*256 + c4*64 + l];
        vv[c4] = F[W_AV + n*256 + c4*64 + l];
    }
    long base = ((long)n*43008 + (long)b*TLEN)*256;
    const u16* pb = proj + base;

    // phase 1: independent per-(t,lane) partials
    for (int i = 0; i < 42; ++i){
        int t = w*42 + i;
        float s = 0.0f;
        #pragma unroll
        for (int c4 = 0; c4 < 4; ++c4){
            float pv = bf2f(pb[(long)t*256 + c4*64 + l]);
            s += vv[c4]*tanh_fast(pv + qv[c4]);
        }
        ps[t][l] = s;
    }
    __syncthreads();

    // phase 2: lane-sum with 8 independent chains (t = tid < 168)
    float sval = 0.0f;
    if (tid < TLEN){
        float s0=0.f,s1=0.f,s2=0.f,s3=0.f,s4=0.f,s5=0.f,s6=0.f,s7=0.f;
        #pragma unroll
        for (int j = 0; j < 64; j += 8){
            s0 += ps[tid][j];   s1 += ps[tid][j+1];
            s2 += ps[tid][j+2]; s3 += ps[tid][j+3];
            s4 += ps[tid][j+4]; s5 += ps[tid][j+5];
            s6 += ps[tid][j+6]; s7 += ps[tid][j+7];
        }
        sval = ((s0+s1)+(s2+s3)) + ((s4+s5)+(s6+s7));
    }

    // parallel max (butterfly + 4-way LDS combine)
    float m = (tid < TLEN) ? sval : -1e30f;
    #pragma unroll
    for (int off = 32; off > 0; off >>= 1) m = fmaxf(m, __shfl_xor(m, off, 64));
    if (l == 0) red[w] = m;
    __syncthreads();
    float mx = fmaxf(fmaxf(red[0],red[1]), fmaxf(red[2],red[3]));

    // exp + parallel sum
    float ex = 0.0f;
    if (tid < TLEN){ ex = __expf(sval - mx); sc[tid] = ex; }
    float su = ex;
    #pragma unroll
    for (int off = 32; off > 0; off >>= 1) su += __shfl_xor(su, off, 64);
    if (l == 0) red[4+w] = su;
    __syncthreads();
    float inv = 1.0f/((red[4]+red[5]) + (red[6]+red[7]));

    // ctx: 8 independent accumulator chains (168 = 8*21)
    const u16* eb = enc16 + base;
    float a0=0.f,a1=0.f,a2=0.f,a3=0.f,a4=0.f,a5=0.f,a6=0.f,a7=0.f;
    for (int t = 0; t < TLEN; t += 8){
        a0 += sc[t  ]*bf2f(eb[(long)(t  )*256 + tid]);
        a1 += sc[t+1]*bf2f(eb[(long)(t+1)*256 + tid]);
        a2 += sc[t+2]*bf2f(eb[(long)(t+2)*256 + tid]);
        a3 += sc[t+3]*bf2f(eb[(long)(t+3)*256 + tid]);
        a4 += sc[t+4]*bf2f(eb[(long)(t+4)*256 + tid]);
        a5 += sc[t+5]*bf2f(eb[(long)(t+5)*256 + tid]);
        a6 += sc[t+6]*bf2f(eb[(long)(t+6)*256 + tid]);
        a7 += sc[t+7]*bf2f(eb[(long)(t+7)*256 + tid]);
    }
    C[(long)b*768 + n*256 + tid] = (((a0+a1)+(a2+a3)) + ((a4+a5)+(a6+a7)))*inv;
    if (b==0 && n==0 && tid==0) put_sent(ws, 4);
}

// =========================================================================
// head1: sp = [h,c] @ out1_W[0:1024] : grid 32 rowtiles8, 256 thr
// =========================================================================
__global__ __launch_bounds__(256) void k_head1(char* ws, const float* h_last)
{
    const float* F = (const float*)(ws+OFF_WF);
    const float* C = (const float*)(ws+OFF_C);
    float* SP = (float*)(ws+OFF_SP);
    const int b0 = blockIdx.x*8;
    const int tid = threadIdx.x;

    __shared__ float A[8][1024];
    for (int i = tid; i < 8192; i += 256){
        int r = i >> 10, k = i & 1023;
        A[r][k] = (k < 256) ? h_last[(long)(b0+r)*256 + k]
                            : C[(long)(b0+r)*768 + (k-256)];
    }
    __syncthreads();

    const float* W = F + W_O1W;
    float acc[8];
    float bc = F[W_O1B + tid];
    #pragma unroll
    for (int r = 0; r < 8; ++r) acc[r] = bc;
    for (int k = 0; k < 1024; ++k){
        float w = W[k*256 + tid];
        #pragma unroll
        for (int r = 0; r < 8; ++r) acc[r] += A[r][k]*w;
    }
    for (int r = 0; r < 8; ++r)
        SP[(long)(b0+r)*256 + tid] = acc[r];
}

// =========================================================================
// ext: E = relu(ext_feat @ ext_W + ext_b) -> bf16 : grid 96, 256 thr
// =========================================================================
__global__ __launch_bounds__(256) void k_ext(const void* ext_feat, char* ws)
{
    const float* F = (const float*)(ws+OFF_WF);
    u16* E = (u16*)(ws+OFF_E);
    int mode = *(const int*)(ws+OFF_FLAG);
    const int r0 = blockIdx.x*64;
    const int tid = threadIdx.x;
    __shared__ float ef[64][16];
    for (int i = tid; i < 1024; i += 256)
        ef[i>>4][i&15] = ldmix(ext_feat, (long)(r0 + (i>>4))*16 + (i&15), mode);
    float wreg[16];
    #pragma unroll
    for (int k = 0; k < 16; ++k) wreg[k] = F[W_EXTW + k*256 + tid];
    float bb = F[W_EXTB + tid];
    __syncthreads();
    for (int r = 0; r < 64; ++r){
        float a = bb;
        #pragma unroll
        for (int k = 0; k < 16; ++k) a += ef[r][k]*wreg[k];
        E[(long)(r0+r)*256 + tid] = f2bf((a > 0.0f) ? a : 0.0f);
    }
}

// =========================================================================
// head2: x1 = relu(sp[b] + E@out1_W[1024:] + b1); out = x1@out2_W + b2
// =========================================================================
__global__ __launch_bounds__(256) void k_head2(char* ws, void* out)
{
    const float* F = (const float*)(ws+OFF_WF);
    const u16* E = (const u16*)(ws+OFF_E);
    const float* SP = (const float*)(ws+OFF_SP);
    int mode = *(const int*)(ws+OFF_FLAG);
    const int r0 = blockIdx.x*16;
    const int tid = threadIdx.x;
    const int w = tid>>6, l = tid&63;

    __shared__ float A[16][256];
    __shared__ float x1[16][257];
    for (int i = tid; i < 4096; i += 256)
        A[i>>8][i&255] = bf2f(E[(long)r0*256 + i]);
    __syncthreads();

    const float* W = F + W_O1W + 1024*256;
    float acc[16];
    float bc = F[W_O1B + tid];
    #pragma unroll
    for (int r = 0; r < 16; ++r) acc[r] = 0.0f;
    for (int k = 0; k < 256; ++k){
        float wv = W[k*256 + tid];
        #pragma unroll
        for (int r = 0; r < 16; ++r) acc[r] += A[r][k]*wv;
    }
    for (int r = 0; r < 16; ++r){
        int g = r0 + r;
        int b = g / HOR;
        float v = acc[r] + SP[(long)b*256 + tid] + bc;
        x1[r][tid] = (v > 0.0f) ? v : 0.0f;
    }
    __syncthreads();

    float w2v[4];
    #pragma unroll
    for (int c4 = 0; c4 < 4; ++c4) w2v[c4] = F[W_O2W + c4*64 + l];
    float b2 = F[W_O2B];
    #pragma unroll
    for (int rr = 0; rr < 4; ++rr){
        int m = w*4 + rr;
        float s = 0.0f;
        #pragma unroll
        for (int c4 = 0; c4 < 4; ++c4) s += x1[m][c4*64 + l]*w2v[c4];
        for (int off = 32; off > 0; off >>= 1) s += __shfl_xor(s, off, 64);
        if (l == 0){
            float val = s + b2;
            long g = r0 + m;
            if (mode == 0) ((u16*)out)[g] = f2bf(val);
            else           ((float*)out)[g] = val;
        }
    }
    if (blockIdx.x==0 && tid==0) put_sent(ws, 5);
}

// =========================================================================
// checker: writes 400+10*i to out[0] if sentinel i missing
// =========================================================================
__global__ __launch_bounds__(64) void MTANet_7593502179851_kernel(char* ws, void* out)
{
    if (threadIdx.x == 0){
        const unsigned int* sent = (const unsigned int*)(ws+OFF_SENT);
        int mode = *(const int*)(ws+OFF_FLAG);
        for (int i = 0; i < 7; ++i){
            if (sent[i] != (SENT_MAGIC | (unsigned int)i)){
                float code = 400.0f + 10.0f*(float)i;
                if (mode == 0) ((u16*)out)[0] = f2bf(code);
                else           ((float*)out)[0] = code;
                break;
            }
        }
    }
}

__global__ __launch_bounds__(64) void k_diag(void* out, float code)
{
    if (threadIdx.x == 0){
        ((u16*)out)[0] = f2bf(code);
        ((float*)out)[1] = code;
    }
}

// =========================================================================
extern "C" void kernel_launch(void* const* d_in, const int* in_sizes, int n_in,
                              void* d_out, int out_size, void* d_ws, size_t ws_size,
                              hipStream_t stream)
{
    char* ws = (char*)d_ws;

    static const int exp_sizes[18] = {
        4128768, 6144, 98304, 73728, 589824, 2304, 196608, 196608, 768,
        590592, 196608, 768, 4096, 256, 327680, 256, 256, 1 };
    int bad_i = -1;
    if (n_in != 18) bad_i = 99;
    else for (int i = 0; i < 18; ++i)
        if (in_sizes[i] != exp_sizes[i]){ bad_i = i; break; }
    if (bad_i >= 0){
        k_diag<<<dim3(1), dim3(64), 0, stream>>>(d_out, 900.0f + (float)bad_i);
        return;
    }
    if (ws_size < (size_t)NEED_BYTES){
        k_diag<<<dim3(1), dim3(64), 0, stream>>>(d_out, 600.0f);
        return;
    }

    P15 wp;
    for (int i = 0; i < 15; ++i) wp.p[i] = d_in[3+i];

    hipError_t le[12];
    for (int i = 0; i < 12; ++i) le[i] = hipSuccess;
    (void)hipGetLastError();
    #define CHK(slot) { hipError_t e_ = hipGetLastError(); if (e_ != hipSuccess && le[slot] == hipSuccess) le[slot] = e_; }

    k_probe<<<dim3(1), dim3(256), 0, stream>>>((const u16*)d_in[3], ws);       CHK(0)
    k_convert<<<dim3(256,15), dim3(256), 0, stream>>>(wp, ws);                 CHK(1)
    k_pack<<<dim3(1152,8), dim3(64), 0, stream>>>(ws);                         CHK(2)
    k_init<<<dim3(1024), dim3(256), 0, stream>>>(ws);                          CHK(3)
    k_enc<<<dim3(16,3), dim3(512), 0, stream>>>(d_in[0], ws, (u16*)(ws+OFF_ENCOUT)); CHK(4)
    k_proj<<<dim3(1344,3), dim3(256), 0, stream>>>(ws);                        CHK(5)

    float* hbuf0 = (float*)(ws+OFF_H0);
    float* hbuf1 = (float*)(ws+OFF_H1);
    float* h_last = hbuf0;
    for (int s = 0; s < HOR; ++s){
        float* h_in  = (s & 1) ? hbuf1 : hbuf0;
        float* h_out = (s & 1) ? hbuf0 : hbuf1;
        k_dec_gru<<<dim3(16,16), dim3(192), 0, stream>>>(ws, h_in, h_out, d_in[1], s); CHK(6)
        k_q<<<dim3(32,3), dim3(256), 0, stream>>>(ws, h_out);                   CHK(7)
        k_attn<<<dim3(256,3), dim3(256), 0, stream>>>(ws);                      CHK(8)
        h_last = h_out;
    }
    k_head1<<<dim3(32), dim3(256), 0, stream>>>(ws, h_last);                   CHK(9)
    k_ext<<<dim3(96), dim3(256), 0, stream>>>(d_in[2], ws);                    CHK(10)
    k_head2<<<dim3(384), dim3(256), 0, stream>>>(ws, d_out);                   CHK(11)
    MTANet_7593502179851_kernel<<<dim3(1), dim3(64), 0, stream>>>(ws, d_out);
    #undef CHK

    for (int i = 0; i < 12; ++i){
        if (le[i] != hipSuccess){
            k_diag<<<dim3(1), dim3(64), 0, stream>>>(d_out, 800.0f + (float)i);
            break;
        }
    }
}